// Round 3
// baseline (315.453 us; speedup 1.0000x reference)
//
#include <hip/hip_runtime.h>

#define D 512
#define H 8
#define HD 64
#define NQ 2048
#define NC 4096
#define SPLIT 8
#define CLEN (NC / SPLIT)   // 512 contexts per split chunk
#define M0 3.0f             // fixed softmax max: scores provably < 3 (see notes)

typedef __attribute__((ext_vector_type(8))) short short8;
typedef __attribute__((ext_vector_type(4))) short short4v;
typedef __attribute__((ext_vector_type(4))) float float4v;

__device__ inline float bf2f(short s) {
    unsigned int u = ((unsigned int)(unsigned short)s) << 16;
    return __builtin_bit_cast(float, u);
}
__device__ inline short f2bf(float f) {
    unsigned int u = __builtin_bit_cast(unsigned int, f);
    u = (u + 0x7FFF + ((u >> 16) & 1)) >> 16;   // round-to-nearest-even
    return (short)u;
}

// ---------------------------------------------------------------------------
// Cast f32 -> bf16 for the 6 MFMA-operand tensors into one contiguous ws
// region. Segments (4-elem units): query_repr 262144 | context_repr 524288 |
// Wq/Wk/Wv/Wo 65536 each. Grid 4096 x 256.
// ---------------------------------------------------------------------------
__global__ __launch_bounds__(256) void cast_all(
    const float* __restrict__ s0, const float* __restrict__ s1,
    const float* __restrict__ s2, const float* __restrict__ s3,
    const float* __restrict__ s4, const float* __restrict__ s5,
    short* __restrict__ dst)
{
    int i = blockIdx.x * 256 + threadIdx.x;
    const float* src; int off;
    if      (i < 262144) { src = s0; off = i; }
    else if (i < 786432) { src = s1; off = i - 262144; }
    else if (i < 851968) { src = s2; off = i - 786432; }
    else if (i < 917504) { src = s3; off = i - 851968; }
    else if (i < 983040) { src = s4; off = i - 917504; }
    else                 { src = s5; off = i - 983040; }
    float4v v = ((const float4v*)src)[off];
    short4v o;
    o.x = f2bf(v.x); o.y = f2bf(v.y); o.z = f2bf(v.z); o.w = f2bf(v.w);
    ((short4v*)dst)[i] = o;
}

// ---------------------------------------------------------------------------
// Pairwise distances, precomputed ONCE (head-independent). Pair layout:
// entry e = q*(NC/2) + (c0>>1) + m  (m in [0,16)) holds
// {dist(q, c0+m), dist(q, c0+16+m)} for tile base c0 (mult of 32).
// ---------------------------------------------------------------------------
__global__ __launch_bounds__(256) void dist_pairs(
    const float* __restrict__ qc, const float* __restrict__ cc,
    float* __restrict__ Dp)
{
    int i = blockIdx.x * 256 + threadIdx.x;      // over NQ*NC/4
    int q  = i >> 10;                            // / (NC/4)
    int j  = i & 1023;
    int c0 = (j >> 3) << 5;
    int l  = (j & 7) * 2;
    float qx = qc[q * 2], qy = qc[q * 2 + 1];
    float4v ca = *(const float4v*)(cc + (c0 + l) * 2);        // xA0 yA0 xA1 yA1
    float4v cb = *(const float4v*)(cc + (c0 + 16 + l) * 2);   // xB0 yB0 xB1 yB1
    float4v o;
    float dx, dy;
    dx = qx - ca.x; dy = qy - ca.y; o.x = sqrtf(dx * dx + dy * dy);
    dx = qx - cb.x; dy = qy - cb.y; o.y = sqrtf(dx * dx + dy * dy);
    dx = qx - ca.z; dy = qy - ca.w; o.z = sqrtf(dx * dx + dy * dy);
    dx = qx - cb.z; dy = qy - cb.w; o.w = sqrtf(dx * dx + dy * dy);
    ((float4v*)Dp)[i] = o;
}

// ---------------------------------------------------------------------------
// GEMM: out[M x D] = X @ W^T + bias. Wave computes 16x64 (4 n-tiles),
// A-frag loaded once per k-step and reused 4x.
// ---------------------------------------------------------------------------
__global__ __launch_bounds__(256) void gemm_bt_bias(
    const short* __restrict__ X, const short* __restrict__ W,
    const float* __restrict__ bias, short* __restrict__ out, int M)
{
    int wave = threadIdx.x >> 6, lane = threadIdx.x & 63;
    int gt = blockIdx.x * 4 + wave;
    int tm = gt >> 3;
    int tg = gt & 7;
    if (tm >= (M >> 4)) return;
    int l15 = lane & 15, quad = lane >> 4;
    const short* xp = X + (tm * 16 + l15) * D + quad * 8;
    const short* wp = W + (tg * 64 + l15) * D + quad * 8;
    float4v a0 = {0,0,0,0}, a1 = {0,0,0,0}, a2 = {0,0,0,0}, a3 = {0,0,0,0};
#pragma unroll
    for (int k = 0; k < D; k += 32) {
        short8 a  = *(const short8*)(xp + k);
        short8 b0 = *(const short8*)(wp + k);
        short8 b1 = *(const short8*)(wp + 16 * D + k);
        short8 b2 = *(const short8*)(wp + 32 * D + k);
        short8 b3 = *(const short8*)(wp + 48 * D + k);
        a0 = __builtin_amdgcn_mfma_f32_16x16x32_bf16(a, b0, a0, 0, 0, 0);
        a1 = __builtin_amdgcn_mfma_f32_16x16x32_bf16(a, b1, a1, 0, 0, 0);
        a2 = __builtin_amdgcn_mfma_f32_16x16x32_bf16(a, b2, a2, 0, 0, 0);
        a3 = __builtin_amdgcn_mfma_f32_16x16x32_bf16(a, b3, a3, 0, 0, 0);
    }
    int orow = tm * 16 + quad * 4;
    float4v accs[4] = {a0, a1, a2, a3};
#pragma unroll
    for (int j = 0; j < 4; j++) {
        int col = tg * 64 + j * 16 + l15;
        float bv = bias[col];
#pragma unroll
        for (int r = 0; r < 4; r++)
            out[(orow + r) * D + col] = f2bf(accs[j][r] + bv);
    }
}

// V^T GEMM with PERMUTED context columns for attn_mfma_split4.
// outT is [D][NC]; within each 32-context block, context offset o is stored
// at position rho^-1(o): o=4a+r -> pos = (a<4 ? 8a : 8(a-4)+4) + r.
// This makes the swapped-QK P fragment's k-order match V's k-order with a
// single contiguous b128 read per PV B-fragment (no shuffles anywhere).
__global__ __launch_bounds__(256) void gemm_bt_bias_vtp(
    const short* __restrict__ X, const short* __restrict__ W,
    const float* __restrict__ bias, short* __restrict__ outT, int M)
{
    int wave = threadIdx.x >> 6, lane = threadIdx.x & 63;
    int gt = blockIdx.x * 4 + wave;
    int tm = gt >> 3;
    int tg = gt & 7;
    if (tm >= (M >> 4)) return;
    int l15 = lane & 15, quad = lane >> 4;
    const short* xp = X + (tm * 16 + l15) * D + quad * 8;
    const short* wp = W + (tg * 64 + l15) * D + quad * 8;
    float4v a0 = {0,0,0,0}, a1 = {0,0,0,0}, a2 = {0,0,0,0}, a3 = {0,0,0,0};
#pragma unroll
    for (int k = 0; k < D; k += 32) {
        short8 a  = *(const short8*)(xp + k);
        short8 b0 = *(const short8*)(wp + k);
        short8 b1 = *(const short8*)(wp + 16 * D + k);
        short8 b2 = *(const short8*)(wp + 32 * D + k);
        short8 b3 = *(const short8*)(wp + 48 * D + k);
        a0 = __builtin_amdgcn_mfma_f32_16x16x32_bf16(a, b0, a0, 0, 0, 0);
        a1 = __builtin_amdgcn_mfma_f32_16x16x32_bf16(a, b1, a1, 0, 0, 0);
        a2 = __builtin_amdgcn_mfma_f32_16x16x32_bf16(a, b2, a2, 0, 0, 0);
        a3 = __builtin_amdgcn_mfma_f32_16x16x32_bf16(a, b3, a3, 0, 0, 0);
    }
    int orow = tm * 16 + quad * 4;               // context base, 4-aligned
    int a = (orow & 31) >> 2;
    int posb = (a < 4) ? (8 * a) : (8 * (a - 4) + 4);
    int cp = (orow & ~31) + posb;                // permuted column base
    float4v accs[4] = {a0, a1, a2, a3};
#pragma unroll
    for (int j = 0; j < 4; j++) {
        int col = tg * 64 + j * 16 + l15;        // d index
        float bv = bias[col];
        short4v o;
#pragma unroll
        for (int r = 0; r < 4; r++) o[r] = f2bf(accs[j][r] + bv);
        *(short4v*)(outT + (size_t)col * M + cp) = o;
    }
}

// Same as gemm_bt_bias but adds f32 residual and writes f32 (LayerNorm input).
__global__ __launch_bounds__(256) void gemm_bt_bias_res_f32(
    const short* __restrict__ X, const short* __restrict__ W,
    const float* __restrict__ bias, const float* __restrict__ resid,
    float* __restrict__ out, int M)
{
    int wave = threadIdx.x >> 6, lane = threadIdx.x & 63;
    int gt = blockIdx.x * 4 + wave;
    int tm = gt >> 3;
    int tg = gt & 7;
    if (tm >= (M >> 4)) return;
    int l15 = lane & 15, quad = lane >> 4;
    const short* xp = X + (tm * 16 + l15) * D + quad * 8;
    const short* wp = W + (tg * 64 + l15) * D + quad * 8;
    float4v a0 = {0,0,0,0}, a1 = {0,0,0,0}, a2 = {0,0,0,0}, a3 = {0,0,0,0};
#pragma unroll
    for (int k = 0; k < D; k += 32) {
        short8 a  = *(const short8*)(xp + k);
        short8 b0 = *(const short8*)(wp + k);
        short8 b1 = *(const short8*)(wp + 16 * D + k);
        short8 b2 = *(const short8*)(wp + 32 * D + k);
        short8 b3 = *(const short8*)(wp + 48 * D + k);
        a0 = __builtin_amdgcn_mfma_f32_16x16x32_bf16(a, b0, a0, 0, 0, 0);
        a1 = __builtin_amdgcn_mfma_f32_16x16x32_bf16(a, b1, a1, 0, 0, 0);
        a2 = __builtin_amdgcn_mfma_f32_16x16x32_bf16(a, b2, a2, 0, 0, 0);
        a3 = __builtin_amdgcn_mfma_f32_16x16x32_bf16(a, b3, a3, 0, 0, 0);
    }
    int orow = tm * 16 + quad * 4;
    float4v accs[4] = {a0, a1, a2, a3};
#pragma unroll
    for (int j = 0; j < 4; j++) {
        int col = tg * 64 + j * 16 + l15;
        float bv = bias[col];
#pragma unroll
        for (int r = 0; r < 4; r++) {
            int q = orow + r;
            out[q * D + col] = accs[j][r] + bv + resid[q * D + col];
        }
    }
}

// ---------------------------------------------------------------------------
// MFMA flash attention v4: context-split, FIXED-MAX softmax (M0), SWAPPED
// QK^T (s = mfma(K, Q)) so each lane holds P for ONE q-row (l15) and 8
// contexts -- exactly the PV A-fragment shape. P never leaves registers:
// NO LDS, NO shuffles, NO barriers. V is read from Vp (V^T with permuted
// context columns, built by gemm_bt_bias_vtp) so P's k-order == V's k-order.
// Depth-1 register prefetch (two named reg buffers, static indexing).
// Block = (64 q, 1 head, 1 chunk of 512 contexts).
// ---------------------------------------------------------------------------
__global__ __launch_bounds__(256) void attn_mfma_split4(
    const short* __restrict__ Q, const short* __restrict__ K,
    const short* __restrict__ Vp, const float* __restrict__ Dp,
    const float* __restrict__ log_scale, const float* __restrict__ bph,
    short* __restrict__ Opart, float* __restrict__ Lpart)
{
    int wave = threadIdx.x >> 6, lane = threadIdx.x & 63;
    int h = blockIdx.y;
    int sp = blockIdx.z;
    int q0 = blockIdx.x * 64 + wave * 16;
    int quad = lane >> 4, l15 = lane & 15;
    int cbase = sp * CLEN;

    const float scale = 0.125f;
    float bh = __expf(log_scale[0]) * bph[h];

    // Q fragment (B-operand of swapped QK): lane holds Q[q=q0+l15][d slice]
    const short* qp = Q + (q0 + l15) * D + h * HD + quad * 8;
    short8 qa0 = *(const short8*)(qp);
    short8 qa1 = *(const short8*)(qp + 32);

    // Dp: lane (quad,l15) reads entries m = 4*quad + r, r=0..3 -> two
    // contiguous float4: float index = (q0+l15)*NC + c0 + 8*quad (+4)
    const float* dbase = Dp + (size_t)(q0 + l15) * NC + 8 * quad;

    float lacc = 0.f;
    float4v O0 = {0,0,0,0}, O1 = {0,0,0,0}, O2 = {0,0,0,0}, O3 = {0,0,0,0};

    const short* kbase = K + l15 * D + h * HD + quad * 8;
    const short* vbase = Vp + (size_t)(h * HD + l15) * NC + quad * 8;

#define LOAD_TILE(c, k00, k01, k10, k11, v0, v1, v2, v3, dA, dB)               \
    {                                                                          \
        const short* kp_ = kbase + (size_t)(c) * D;                            \
        k00 = *(const short8*)(kp_);                                           \
        k01 = *(const short8*)(kp_ + 32);                                      \
        k10 = *(const short8*)(kp_ + 16 * D);                                  \
        k11 = *(const short8*)(kp_ + 16 * D + 32);                             \
        const short* vp_ = vbase + (c);                                        \
        v0 = *(const short8*)(vp_);                                            \
        v1 = *(const short8*)(vp_ + 16 * NC);                                  \
        v2 = *(const short8*)(vp_ + 32 * NC);                                  \
        v3 = *(const short8*)(vp_ + 48 * NC);                                  \
        dA = *(const float4v*)(dbase + (c));                                   \
        dB = *(const float4v*)(dbase + (c) + 4);                               \
    }

    // Swapped QK: s0 rows = contexts c0+4*quad+r, s1 rows = c0+16+4*quad+r,
    // col = q = l15. pa k-order (j=0..3 -> s0 regs, j=4..7 -> s1 regs)
    // matches Vp's permuted column order by construction.
#define COMPUTE_TILE(k00, k01, k10, k11, v0, v1, v2, v3, dA, dB)               \
    {                                                                          \
        float4v s0 = {0,0,0,0}, s1 = {0,0,0,0};                                \
        s0 = __builtin_amdgcn_mfma_f32_16x16x32_bf16(k00, qa0, s0, 0, 0, 0);   \
        s0 = __builtin_amdgcn_mfma_f32_16x16x32_bf16(k01, qa1, s0, 0, 0, 0);   \
        s1 = __builtin_amdgcn_mfma_f32_16x16x32_bf16(k10, qa0, s1, 0, 0, 0);   \
        s1 = __builtin_amdgcn_mfma_f32_16x16x32_bf16(k11, qa1, s1, 0, 0, 0);   \
        float p00 = __expf(__fmaf_rn(s0[0], scale, __fmaf_rn(-bh, dA.x, -M0)));\
        float p10 = __expf(__fmaf_rn(s1[0], scale, __fmaf_rn(-bh, dA.y, -M0)));\
        float p01 = __expf(__fmaf_rn(s0[1], scale, __fmaf_rn(-bh, dA.z, -M0)));\
        float p11 = __expf(__fmaf_rn(s1[1], scale, __fmaf_rn(-bh, dA.w, -M0)));\
        float p02 = __expf(__fmaf_rn(s0[2], scale, __fmaf_rn(-bh, dB.x, -M0)));\
        float p12 = __expf(__fmaf_rn(s1[2], scale, __fmaf_rn(-bh, dB.y, -M0)));\
        float p03 = __expf(__fmaf_rn(s0[3], scale, __fmaf_rn(-bh, dB.z, -M0)));\
        float p13 = __expf(__fmaf_rn(s1[3], scale, __fmaf_rn(-bh, dB.w, -M0)));\
        lacc += ((p00 + p10) + (p01 + p11)) + ((p02 + p12) + (p03 + p13));     \
        short8 pa;                                                             \
        pa[0] = f2bf(p00); pa[1] = f2bf(p01); pa[2] = f2bf(p02);               \
        pa[3] = f2bf(p03); pa[4] = f2bf(p10); pa[5] = f2bf(p11);               \
        pa[6] = f2bf(p12); pa[7] = f2bf(p13);                                  \
        O0 = __builtin_amdgcn_mfma_f32_16x16x32_bf16(pa, v0, O0, 0, 0, 0);     \
        O1 = __builtin_amdgcn_mfma_f32_16x16x32_bf16(pa, v1, O1, 0, 0, 0);     \
        O2 = __builtin_amdgcn_mfma_f32_16x16x32_bf16(pa, v2, O2, 0, 0, 0);     \
        O3 = __builtin_amdgcn_mfma_f32_16x16x32_bf16(pa, v3, O3, 0, 0, 0);     \
    }

    short8 Ak00, Ak01, Ak10, Ak11, Av0, Av1, Av2, Av3;
    float4v AdA, AdB;
    short8 Bk00, Bk01, Bk10, Bk11, Bv0, Bv1, Bv2, Bv3;
    float4v BdA, BdB;

    LOAD_TILE(cbase, Ak00, Ak01, Ak10, Ak11, Av0, Av1, Av2, Av3, AdA, AdB);

    const int NT = CLEN / 32;   // 16 tiles, even
    for (int t = 0; t < NT; t += 2) {
        int cA = cbase + t * 32;
        int cB = cA + 32;                                   // t+1 < NT always
        LOAD_TILE(cB, Bk00, Bk01, Bk10, Bk11, Bv0, Bv1, Bv2, Bv3, BdA, BdB);
        COMPUTE_TILE(Ak00, Ak01, Ak10, Ak11, Av0, Av1, Av2, Av3, AdA, AdB);
        int cC = (t + 2 < NT) ? cA + 64 : cbase;            // tail: dummy addr
        LOAD_TILE(cC, Ak00, Ak01, Ak10, Ak11, Av0, Av1, Av2, Av3, AdA, AdB);
        COMPUTE_TILE(Bk00, Bk01, Bk10, Bk11, Bv0, Bv1, Bv2, Bv3, BdA, BdB);
    }
#undef LOAD_TILE
#undef COMPUTE_TILE

    // L reduction: sum per q=l15 across the 4 quads (lanes +-16, +-32)
    lacc += __shfl_xor(lacc, 16);
    lacc += __shfl_xor(lacc, 32);

    long base = (long)(sp * H + h) * NQ;
    // O layout: lane holds O[q = q0 + quad*4 + r][d = t*16 + l15]
    float4v Oarr[4] = {O0, O1, O2, O3};
#pragma unroll
    for (int t = 0; t < 4; t++) {
#pragma unroll
        for (int r = 0; r < 4; r++) {
            int q = q0 + quad * 4 + r;
            Opart[(base + q) * HD + t * 16 + l15] = f2bf(Oarr[t][r]);
        }
    }
    if (lane < 16)
        Lpart[base + q0 + lane] = lacc;
}

// Plain-sum combine (all splits share fixed max M0) -> bf16 Att.
__global__ __launch_bounds__(256) void attn_combine(
    const short* __restrict__ Opart, const float* __restrict__ Lpart,
    short* __restrict__ Att)
{
    int id = blockIdx.x * 256 + threadIdx.x;   // over H*NQ*HD = 2^20
    int d = id & 63;
    int q = (id >> 6) & (NQ - 1);
    int h = id >> 17;
    float L = 0.f, acc = 0.f;
#pragma unroll
    for (int s = 0; s < SPLIT; s++) {
        long b = (long)(s * H + h) * NQ + q;
        L   += Lpart[b];
        acc += bf2f(Opart[b * HD + d]);
    }
    Att[q * D + h * HD + d] = f2bf(acc / L);
}

// ---------------------------------------------------------------------------
// OLD split attention (V in LDS, coords in-kernel) — mid-size-ws fallback.
// ---------------------------------------------------------------------------
__global__ __launch_bounds__(256) void attn_mfma_split(
    const short* __restrict__ Q, const short* __restrict__ K,
    const short* __restrict__ V,
    const float* __restrict__ qc, const float* __restrict__ cc,
    const float* __restrict__ log_scale, const float* __restrict__ bph,
    short* __restrict__ Opart, float* __restrict__ Lpart)
{
    __shared__ short Vt[HD][48];
    __shared__ short P[4][16][48];

    int wave = threadIdx.x >> 6, lane = threadIdx.x & 63;
    int h = blockIdx.y;
    int sp = blockIdx.z;
    int q0 = blockIdx.x * 64 + wave * 16;
    int quad = lane >> 4, l15 = lane & 15;
    int cbase = sp * CLEN;

    const float scale = 0.125f;
    float bh = __expf(log_scale[0]) * bph[h];

    const short* qp = Q + (q0 + l15) * D + h * HD + quad * 8;
    short8 qa0 = *(const short8*)(qp);
    short8 qa1 = *(const short8*)(qp + 32);

    float qx[4], qy[4];
#pragma unroll
    for (int r = 0; r < 4; r++) {
        int q = q0 + quad * 4 + r;
        qx[r] = qc[q * 2];
        qy[r] = qc[q * 2 + 1];
    }

    float lacc[4] = {0.f, 0.f, 0.f, 0.f};
    float4v O[4];
#pragma unroll
    for (int t = 0; t < 4; t++) O[t] = (float4v){0.f, 0.f, 0.f, 0.f};

    for (int c0 = cbase; c0 < cbase + CLEN; c0 += 32) {
        __syncthreads();
        {
            int c = threadIdx.x >> 3;
            int dblk = (threadIdx.x & 7) * 8;
            short8 vv = *(const short8*)(V + (c0 + c) * D + h * HD + dblk);
#pragma unroll
            for (int j = 0; j < 8; j++) Vt[dblk + j][c] = vv[j];
        }
        const short* kp0 = K + (c0 + l15) * D + h * HD + quad * 8;
        const short* kp1 = kp0 + 16 * D;
        short8 kb00 = *(const short8*)(kp0);
        short8 kb01 = *(const short8*)(kp0 + 32);
        short8 kb10 = *(const short8*)(kp1);
        short8 kb11 = *(const short8*)(kp1 + 32);
        float4v s0 = {0,0,0,0}, s1 = {0,0,0,0};
        s0 = __builtin_amdgcn_mfma_f32_16x16x32_bf16(qa0, kb00, s0, 0, 0, 0);
        s0 = __builtin_amdgcn_mfma_f32_16x16x32_bf16(qa1, kb01, s0, 0, 0, 0);
        s1 = __builtin_amdgcn_mfma_f32_16x16x32_bf16(qa0, kb10, s1, 0, 0, 0);
        s1 = __builtin_amdgcn_mfma_f32_16x16x32_bf16(qa1, kb11, s1, 0, 0, 0);

        int cA = c0 + l15, cB = cA + 16;
        float cxA = cc[cA * 2], cyA = cc[cA * 2 + 1];
        float cxB = cc[cB * 2], cyB = cc[cB * 2 + 1];
#pragma unroll
        for (int r = 0; r < 4; r++) {
            float dxA = qx[r] - cxA, dyA = qy[r] - cyA;
            float dxB = qx[r] - cxB, dyB = qy[r] - cyB;
            float p0 = __expf(s0[r] * scale - bh * sqrtf(dxA * dxA + dyA * dyA) - M0);
            float p1 = __expf(s1[r] * scale - bh * sqrtf(dxB * dxB + dyB * dyB) - M0);
            lacc[r] += p0 + p1;
            P[wave][quad * 4 + r][l15]      = f2bf(p0);
            P[wave][quad * 4 + r][16 + l15] = f2bf(p1);
        }
        __syncthreads();
        short8 pa = *(const short8*)(&P[wave][l15][quad * 8]);
#pragma unroll
        for (int t = 0; t < 4; t++) {
            short8 vb = *(const short8*)(&Vt[t * 16 + l15][quad * 8]);
            O[t] = __builtin_amdgcn_mfma_f32_16x16x32_bf16(pa, vb, O[t], 0, 0, 0);
        }
    }
#pragma unroll
    for (int r = 0; r < 4; r++) {
#pragma unroll
        for (int off = 1; off < 16; off <<= 1)
            lacc[r] += __shfl_xor(lacc[r], off);
    }
    long base = (long)(sp * H + h) * NQ;
#pragma unroll
    for (int t = 0; t < 4; t++) {
#pragma unroll
        for (int r = 0; r < 4; r++) {
            int q = q0 + quad * 4 + r;
            Opart[(base + q) * HD + t * 16 + l15] = f2bf(O[t][r]);
        }
    }
    if (l15 == 0) {
#pragma unroll
        for (int r = 0; r < 4; r++)
            Lpart[base + q0 + quad * 4 + r] = lacc[r];
    }
}

// ---------------------------------------------------------------------------
// Fallback single-pass attention (exact online softmax) if ws is too small.
// ---------------------------------------------------------------------------
__global__ __launch_bounds__(256) void attn_mfma(
    const short* __restrict__ Q, const short* __restrict__ K,
    const short* __restrict__ V,
    const float* __restrict__ qc, const float* __restrict__ cc,
    const float* __restrict__ log_scale, const float* __restrict__ bph,
    short* __restrict__ out)
{
    __shared__ short Vt[HD][48];
    __shared__ short P[4][16][48];
    int wave = threadIdx.x >> 6, lane = threadIdx.x & 63;
    int h = blockIdx.y;
    int q0 = blockIdx.x * 64 + wave * 16;
    int quad = lane >> 4, l15 = lane & 15;
    const float scale = 0.125f;
    float bh = __expf(log_scale[0]) * bph[h];
    const short* qp = Q + (q0 + l15) * D + h * HD + quad * 8;
    short8 qa0 = *(const short8*)(qp);
    short8 qa1 = *(const short8*)(qp + 32);
    float qx[4], qy[4];
#pragma unroll
    for (int r = 0; r < 4; r++) {
        int q = q0 + quad * 4 + r;
        qx[r] = qc[q * 2]; qy[r] = qc[q * 2 + 1];
    }
    float m[4], l[4];
    float4v O[4];
#pragma unroll
    for (int r = 0; r < 4; r++) { m[r] = -1e30f; l[r] = 0.f; }
#pragma unroll
    for (int t = 0; t < 4; t++) O[t] = (float4v){0.f, 0.f, 0.f, 0.f};
    for (int c0 = 0; c0 < NC; c0 += 32) {
        __syncthreads();
        {
            int c = threadIdx.x >> 3;
            int dblk = (threadIdx.x & 7) * 8;
            short8 vv = *(const short8*)(V + (c0 + c) * D + h * HD + dblk);
#pragma unroll
            for (int j = 0; j < 8; j++) Vt[dblk + j][c] = vv[j];
        }
        const short* kp0 = K + (c0 + l15) * D + h * HD + quad * 8;
        const short* kp1 = kp0 + 16 * D;
        short8 kb00 = *(const short8*)(kp0);
        short8 kb01 = *(const short8*)(kp0 + 32);
        short8 kb10 = *(const short8*)(kp1);
        short8 kb11 = *(const short8*)(kp1 + 32);
        float4v s0 = {0,0,0,0}, s1 = {0,0,0,0};
        s0 = __builtin_amdgcn_mfma_f32_16x16x32_bf16(qa0, kb00, s0, 0, 0, 0);
        s0 = __builtin_amdgcn_mfma_f32_16x16x32_bf16(qa1, kb01, s0, 0, 0, 0);
        s1 = __builtin_amdgcn_mfma_f32_16x16x32_bf16(qa0, kb10, s1, 0, 0, 0);
        s1 = __builtin_amdgcn_mfma_f32_16x16x32_bf16(qa1, kb11, s1, 0, 0, 0);
        int cA = c0 + l15, cB = cA + 16;
        float cxA = cc[cA * 2], cyA = cc[cA * 2 + 1];
        float cxB = cc[cB * 2], cyB = cc[cB * 2 + 1];
#pragma unroll
        for (int r = 0; r < 4; r++) {
            float dxA = qx[r] - cxA, dyA = qy[r] - cyA;
            float dxB = qx[r] - cxB, dyB = qy[r] - cyB;
            float v0 = s0[r] * scale - bh * sqrtf(dxA * dxA + dyA * dyA);
            float v1 = s1[r] * scale - bh * sqrtf(dxB * dxB + dyB * dyB);
            float mx = fmaxf(v0, v1);
#pragma unroll
            for (int off = 1; off < 16; off <<= 1) mx = fmaxf(mx, __shfl_xor(mx, off));
            float mnew = fmaxf(m[r], mx);
            float alpha = __expf(m[r] - mnew);
            float p0 = __expf(v0 - mnew);
            float p1 = __expf(v1 - mnew);
            float ps = p0 + p1;
#pragma unroll
            for (int off = 1; off < 16; off <<= 1) ps += __shfl_xor(ps, off);
            l[r] = l[r] * alpha + ps;
            m[r] = mnew;
#pragma unroll
            for (int t = 0; t < 4; t++) O[t][r] *= alpha;
            P[wave][quad * 4 + r][l15]      = f2bf(p0);
            P[wave][quad * 4 + r][16 + l15] = f2bf(p1);
        }
        __syncthreads();
        short8 pa = *(const short8*)(&P[wave][l15][quad * 8]);
#pragma unroll
        for (int t = 0; t < 4; t++) {
            short8 vb = *(const short8*)(&Vt[t * 16 + l15][quad * 8]);
            O[t] = __builtin_amdgcn_mfma_f32_16x16x32_bf16(pa, vb, O[t], 0, 0, 0);
        }
    }
#pragma unroll
    for (int t = 0; t < 4; t++) {
#pragma unroll
        for (int r = 0; r < 4; r++) {
            int q = q0 + quad * 4 + r;
            out[q * D + h * HD + t * 16 + l15] = f2bf(O[t][r] / l[r]);
        }
    }
}

// ---------------------------------------------------------------------------
// Row LayerNorm: one wave per row of 512 f32, output f32.
// ---------------------------------------------------------------------------
__global__ __launch_bounds__(256) void layernorm_kernel(
    const float* __restrict__ X, const float* __restrict__ g,
    const float* __restrict__ b, float* __restrict__ out)
{
    int wave = threadIdx.x >> 6, lane = threadIdx.x & 63;
    int row = blockIdx.x * 4 + wave;
    const float* xp = X + row * D;
    float v[8];
    float s = 0.f;
#pragma unroll
    for (int i = 0; i < 8; i++) { v[i] = xp[lane + i * 64]; s += v[i]; }
#pragma unroll
    for (int off = 1; off < 64; off <<= 1) s += __shfl_xor(s, off);
    float mu = s * (1.f / D);
    float var = 0.f;
#pragma unroll
    for (int i = 0; i < 8; i++) { float d = v[i] - mu; var += d * d; }
#pragma unroll
    for (int off = 1; off < 64; off <<= 1) var += __shfl_xor(var, off);
    float rstd = rsqrtf(var * (1.f / D) + 1e-5f);
#pragma unroll
    for (int i = 0; i < 8; i++) {
        int c = lane + i * 64;
        out[row * D + c] = (v[i] - mu) * rstd * g[c] + b[c];
    }
}

extern "C" void kernel_launch(void* const* d_in, const int* in_sizes, int n_in,
                              void* d_out, int out_size, void* d_ws, size_t ws_size,
                              hipStream_t stream) {
    const float* query_repr     = (const float*)d_in[0];
    const float* context_repr   = (const float*)d_in[1];
    const float* query_coords   = (const float*)d_in[2];
    const float* context_coords = (const float*)d_in[3];
    const float* Wq = (const float*)d_in[4];
    const float* bq = (const float*)d_in[5];
    const float* Wk = (const float*)d_in[6];
    const float* bk = (const float*)d_in[7];
    const float* Wv = (const float*)d_in[8];
    const float* bv = (const float*)d_in[9];
    const float* Wo = (const float*)d_in[10];
    const float* bo = (const float*)d_in[11];
    const float* ln_g = (const float*)d_in[12];
    const float* ln_b = (const float*)d_in[13];
    const float* log_scale = (const float*)d_in[14];
    const float* bph = (const float*)d_in[15];

    short* ws = (short*)d_ws;
    short* Xq_bf = ws;                       // 1,048,576 shorts
    short* Xc_bf = Xq_bf + NQ * D;           // 2,097,152
    short* Wq_bf = Xc_bf + NC * D;           //   262,144 x4
    short* Wk_bf = Wq_bf + D * D;
    short* Wv_bf = Wk_bf + D * D;
    short* Wo_bf = Wv_bf + D * D;
    short* Qw  = Wo_bf + D * D;              // 1,048,576
    short* Kw  = Qw + NQ * D;                // 2,097,152
    short* Vw  = Kw + NC * D;                // 2,097,152 (new path: Vp [D][NC] permuted)
    short* Att = Vw + NC * D;                // 1,048,576
    float* Xf  = (float*)(Att + NQ * D);     // 1,048,576 f32
    short* Opart = (short*)(Xf + NQ * D);    // SPLIT*H*NQ*HD bf16 = 16.8 MB
    float* Lpart = (float*)(Opart + (size_t)SPLIT * H * NQ * HD);  // 0.5 MB
    float* Dpair = Lpart + (size_t)SPLIT * H * NQ;                 // 33.5 MB f32
    size_t ws_needed_split = ((char*)Dpair) - (char*)d_ws;
    size_t ws_needed_new   = ((char*)(Dpair + (size_t)NQ * NC)) - (char*)d_ws;

    // 1. cast MFMA operands to bf16
    cast_all<<<dim3(4096), 256, 0, stream>>>(
        query_repr, context_repr, Wq, Wk, Wv, Wo, Xq_bf);

    // 2. Q/K projections (MFMA, 16x64 per wave)
    gemm_bt_bias<<<dim3((NQ / 16) * 8 / 4), 256, 0, stream>>>(Xq_bf, Wq_bf, bq, Qw, NQ);
    gemm_bt_bias<<<dim3((NC / 16) * 8 / 4), 256, 0, stream>>>(Xc_bf, Wk_bf, bk, Kw, NC);

    // 3. V projection + attention
    if (ws_size >= ws_needed_new) {
        // V stored transposed+permuted [D][NC]; dist precomputed once;
        // attention v4: swapped QK, in-register P, no LDS, no barriers.
        gemm_bt_bias_vtp<<<dim3((NC / 16) * 8 / 4), 256, 0, stream>>>(
            Xc_bf, Wv_bf, bv, Vw, NC);
        dist_pairs<<<dim3(NQ * NC / 4 / 256), 256, 0, stream>>>(
            query_coords, context_coords, Dpair);
        attn_mfma_split4<<<dim3(NQ / 64, H, SPLIT), 256, 0, stream>>>(
            Qw, Kw, Vw, Dpair, log_scale, bph, Opart, Lpart);
        attn_combine<<<dim3(H * NQ * HD / 256), 256, 0, stream>>>(
            Opart, Lpart, Att);
    } else {
        gemm_bt_bias<<<dim3((NC / 16) * 8 / 4), 256, 0, stream>>>(
            Xc_bf, Wv_bf, bv, Vw, NC);
        if (ws_size >= ws_needed_split) {
            attn_mfma_split<<<dim3(NQ / 64, H, SPLIT), 256, 0, stream>>>(
                Qw, Kw, Vw, query_coords, context_coords, log_scale, bph,
                Opart, Lpart);
            attn_combine<<<dim3(H * NQ * HD / 256), 256, 0, stream>>>(
                Opart, Lpart, Att);
        } else {
            attn_mfma<<<dim3(NQ / 64, H), 256, 0, stream>>>(
                Qw, Kw, Vw, query_coords, context_coords, log_scale, bph, Att);
        }
    }

    // 4. output projection + residual (MFMA, f32 out)
    gemm_bt_bias_res_f32<<<dim3((NQ / 16) * 8 / 4), 256, 0, stream>>>(
        Att, Wo_bf, bo, query_repr, Xf, NQ);

    // 5. LayerNorm -> f32 output
    layernorm_kernel<<<dim3(NQ / 4), 256, 0, stream>>>(Xf, ln_g, ln_b, (float*)d_out);
}

// Round 4
// 223.306 us; speedup vs baseline: 1.4127x; 1.4127x over previous
//
#include <hip/hip_runtime.h>

#define D 512
#define H 8
#define HD 64
#define NQ 2048
#define NC 4096
#define SPLIT 8
#define CLEN (NC / SPLIT)   // 512 contexts per split chunk
#define NT (CLEN / 32)      // 16 tiles per chunk
#define M0 3.0f             // fixed softmax max: scores provably < 3 (see notes)
#define KP 72               // K LDS row stride (shorts), 144B: 16B-aligned, 2-way banks
#define VP 40               // V LDS row stride (shorts), 80B: 16B-aligned, 2-way banks

typedef __attribute__((ext_vector_type(8))) short short8;
typedef __attribute__((ext_vector_type(4))) short short4v;
typedef __attribute__((ext_vector_type(4))) float float4v;

__device__ inline float bf2f(short s) {
    unsigned int u = ((unsigned int)(unsigned short)s) << 16;
    return __builtin_bit_cast(float, u);
}
__device__ inline short f2bf(float f) {
    unsigned int u = __builtin_bit_cast(unsigned int, f);
    u = (u + 0x7FFF + ((u >> 16) & 1)) >> 16;   // round-to-nearest-even
    return (short)u;
}

// ---------------------------------------------------------------------------
// Cast f32 -> bf16 for the 6 MFMA-operand tensors into one contiguous ws
// region. Grid 4096 x 256.
// ---------------------------------------------------------------------------
__global__ __launch_bounds__(256) void cast_all(
    const float* __restrict__ s0, const float* __restrict__ s1,
    const float* __restrict__ s2, const float* __restrict__ s3,
    const float* __restrict__ s4, const float* __restrict__ s5,
    short* __restrict__ dst)
{
    int i = blockIdx.x * 256 + threadIdx.x;
    const float* src; int off;
    if      (i < 262144) { src = s0; off = i; }
    else if (i < 786432) { src = s1; off = i - 262144; }
    else if (i < 851968) { src = s2; off = i - 786432; }
    else if (i < 917504) { src = s3; off = i - 851968; }
    else if (i < 983040) { src = s4; off = i - 917504; }
    else                 { src = s5; off = i - 983040; }
    float4v v = ((const float4v*)src)[off];
    short4v o;
    o.x = f2bf(v.x); o.y = f2bf(v.y); o.z = f2bf(v.z); o.w = f2bf(v.w);
    ((short4v*)dst)[i] = o;
}

// ---------------------------------------------------------------------------
// GEMM: out[M x D] = X @ W^T + bias. Wave computes 16x64 (4 n-tiles).
// ---------------------------------------------------------------------------
__global__ __launch_bounds__(256) void gemm_bt_bias(
    const short* __restrict__ X, const short* __restrict__ W,
    const float* __restrict__ bias, short* __restrict__ out, int M)
{
    int wave = threadIdx.x >> 6, lane = threadIdx.x & 63;
    int gt = blockIdx.x * 4 + wave;
    int tm = gt >> 3;
    int tg = gt & 7;
    if (tm >= (M >> 4)) return;
    int l15 = lane & 15, quad = lane >> 4;
    const short* xp = X + (tm * 16 + l15) * D + quad * 8;
    const short* wp = W + (tg * 64 + l15) * D + quad * 8;
    float4v a0 = {0,0,0,0}, a1 = {0,0,0,0}, a2 = {0,0,0,0}, a3 = {0,0,0,0};
#pragma unroll
    for (int k = 0; k < D; k += 32) {
        short8 a  = *(const short8*)(xp + k);
        short8 b0 = *(const short8*)(wp + k);
        short8 b1 = *(const short8*)(wp + 16 * D + k);
        short8 b2 = *(const short8*)(wp + 32 * D + k);
        short8 b3 = *(const short8*)(wp + 48 * D + k);
        a0 = __builtin_amdgcn_mfma_f32_16x16x32_bf16(a, b0, a0, 0, 0, 0);
        a1 = __builtin_amdgcn_mfma_f32_16x16x32_bf16(a, b1, a1, 0, 0, 0);
        a2 = __builtin_amdgcn_mfma_f32_16x16x32_bf16(a, b2, a2, 0, 0, 0);
        a3 = __builtin_amdgcn_mfma_f32_16x16x32_bf16(a, b3, a3, 0, 0, 0);
    }
    int orow = tm * 16 + quad * 4;
    float4v accs[4] = {a0, a1, a2, a3};
#pragma unroll
    for (int j = 0; j < 4; j++) {
        int col = tg * 64 + j * 16 + l15;
        float bv = bias[col];
#pragma unroll
        for (int r = 0; r < 4; r++)
            out[(orow + r) * D + col] = f2bf(accs[j][r] + bv);
    }
}

// V^T GEMM with PERMUTED context columns (verified in round 3).
// outT is [D][NC]; within each 32-context block, context o = 4a+r stored at
// pos (a<4 ? 8a : 8(a-4)+4) + r, matching the swapped-QK P fragment k-order.
__global__ __launch_bounds__(256) void gemm_bt_bias_vtp(
    const short* __restrict__ X, const short* __restrict__ W,
    const float* __restrict__ bias, short* __restrict__ outT, int M)
{
    int wave = threadIdx.x >> 6, lane = threadIdx.x & 63;
    int gt = blockIdx.x * 4 + wave;
    int tm = gt >> 3;
    int tg = gt & 7;
    if (tm >= (M >> 4)) return;
    int l15 = lane & 15, quad = lane >> 4;
    const short* xp = X + (tm * 16 + l15) * D + quad * 8;
    const short* wp = W + (tg * 64 + l15) * D + quad * 8;
    float4v a0 = {0,0,0,0}, a1 = {0,0,0,0}, a2 = {0,0,0,0}, a3 = {0,0,0,0};
#pragma unroll
    for (int k = 0; k < D; k += 32) {
        short8 a  = *(const short8*)(xp + k);
        short8 b0 = *(const short8*)(wp + k);
        short8 b1 = *(const short8*)(wp + 16 * D + k);
        short8 b2 = *(const short8*)(wp + 32 * D + k);
        short8 b3 = *(const short8*)(wp + 48 * D + k);
        a0 = __builtin_amdgcn_mfma_f32_16x16x32_bf16(a, b0, a0, 0, 0, 0);
        a1 = __builtin_amdgcn_mfma_f32_16x16x32_bf16(a, b1, a1, 0, 0, 0);
        a2 = __builtin_amdgcn_mfma_f32_16x16x32_bf16(a, b2, a2, 0, 0, 0);
        a3 = __builtin_amdgcn_mfma_f32_16x16x32_bf16(a, b3, a3, 0, 0, 0);
    }
    int orow = tm * 16 + quad * 4;               // context base, 4-aligned
    int a = (orow & 31) >> 2;
    int posb = (a < 4) ? (8 * a) : (8 * (a - 4) + 4);
    int cp = (orow & ~31) + posb;                // permuted column base
    float4v accs[4] = {a0, a1, a2, a3};
#pragma unroll
    for (int j = 0; j < 4; j++) {
        int col = tg * 64 + j * 16 + l15;        // d index
        float bv = bias[col];
        short4v o;
#pragma unroll
        for (int r = 0; r < 4; r++) o[r] = f2bf(accs[j][r] + bv);
        *(short4v*)(outT + (size_t)col * M + cp) = o;
    }
}

// Same as gemm_bt_bias but adds f32 residual and writes f32 (LayerNorm input).
__global__ __launch_bounds__(256) void gemm_bt_bias_res_f32(
    const short* __restrict__ X, const short* __restrict__ W,
    const float* __restrict__ bias, const float* __restrict__ resid,
    float* __restrict__ out, int M)
{
    int wave = threadIdx.x >> 6, lane = threadIdx.x & 63;
    int gt = blockIdx.x * 4 + wave;
    int tm = gt >> 3;
    int tg = gt & 7;
    if (tm >= (M >> 4)) return;
    int l15 = lane & 15, quad = lane >> 4;
    const short* xp = X + (tm * 16 + l15) * D + quad * 8;
    const short* wp = W + (tg * 64 + l15) * D + quad * 8;
    float4v a0 = {0,0,0,0}, a1 = {0,0,0,0}, a2 = {0,0,0,0}, a3 = {0,0,0,0};
#pragma unroll
    for (int k = 0; k < D; k += 32) {
        short8 a  = *(const short8*)(xp + k);
        short8 b0 = *(const short8*)(wp + k);
        short8 b1 = *(const short8*)(wp + 16 * D + k);
        short8 b2 = *(const short8*)(wp + 32 * D + k);
        short8 b3 = *(const short8*)(wp + 48 * D + k);
        a0 = __builtin_amdgcn_mfma_f32_16x16x32_bf16(a, b0, a0, 0, 0, 0);
        a1 = __builtin_amdgcn_mfma_f32_16x16x32_bf16(a, b1, a1, 0, 0, 0);
        a2 = __builtin_amdgcn_mfma_f32_16x16x32_bf16(a, b2, a2, 0, 0, 0);
        a3 = __builtin_amdgcn_mfma_f32_16x16x32_bf16(a, b3, a3, 0, 0, 0);
    }
    int orow = tm * 16 + quad * 4;
    float4v accs[4] = {a0, a1, a2, a3};
#pragma unroll
    for (int j = 0; j < 4; j++) {
        int col = tg * 64 + j * 16 + l15;
        float bv = bias[col];
#pragma unroll
        for (int r = 0; r < 4; r++) {
            int q = orow + r;
            out[q * D + col] = accs[j][r] + bv + resid[q * D + col];
        }
    }
}

// ---------------------------------------------------------------------------
// MFMA flash attention v5: swapped-QK in-register P (verified v4 core) +
// COALESCED SHARED STAGING (fix of v4's 16-line gathers):
//  - K-tile [32 ctx][64 d] and V-tile [64 d][32 ctx, rho-permuted] staged
//    into padded LDS (double-buffered) via coalesced b128 loads, SHARED by
//    all 4 waves (v4: each wave gathered the same tile itself, 4x traffic).
//  - distances computed in-kernel from coords (cc staged once in LDS,
//    read as free same-address broadcasts) -- no Dp tensor, no 33.5 MB.
//  - 1 barrier per tile; loads for t+2 issued before compute of t.
// Block = (64 q, 1 head, 1 chunk of 512 contexts).
// ---------------------------------------------------------------------------
__global__ __launch_bounds__(256) void attn_mfma_split5(
    const short* __restrict__ Q, const short* __restrict__ K,
    const short* __restrict__ Vp,
    const float* __restrict__ qc, const float* __restrict__ cc,
    const float* __restrict__ log_scale, const float* __restrict__ bph,
    short* __restrict__ Opart, float* __restrict__ Lpart)
{
    __shared__ __align__(16) short Klds[2][32 * KP];
    __shared__ __align__(16) short Vlds[2][64 * VP];
    __shared__ __align__(16) float ccl[CLEN * 2];

    int tid = threadIdx.x;
    int wave = tid >> 6, lane = tid & 63;
    int h = blockIdx.y;
    int sp = blockIdx.z;
    int q0 = blockIdx.x * 64 + wave * 16;
    int quad = lane >> 4, l15 = lane & 15;
    int cbase = sp * CLEN;

    const float scale = 0.125f;
    float bh = __expf(log_scale[0]) * bph[h];

    // Q fragment (B-operand of swapped QK): lane holds Q[q=q0+l15][d slice]
    const short* qp = Q + (q0 + l15) * D + h * HD + quad * 8;
    short8 qa0 = *(const short8*)(qp);
    short8 qa1 = *(const short8*)(qp + 32);

    // this lane's query coords (q = q0 + l15 in the swapped layout)
    float qx = qc[(q0 + l15) * 2];
    float qy = qc[(q0 + l15) * 2 + 1];

    float lacc = 0.f;
    float4v O0 = {0,0,0,0}, O1 = {0,0,0,0}, O2 = {0,0,0,0}, O3 = {0,0,0,0};

    // staging thread map (256 threads):
    //  K tile: 32 rows x 64 shorts: thread i -> row i>>3, 16B chunk i&7
    //  V tile: 64 rows x 32 shorts: thread i -> row i>>2, 16B chunk i&3
    int kr_ = tid >> 3, kc_ = tid & 7;
    int vr_ = tid >> 2, vc_ = tid & 3;
    const short* kgbase = K + (size_t)h * HD + kc_ * 8;   // + (c0+kr_)*D
    const short* vgbase = Vp + (size_t)(h * HD + vr_) * NC + vc_ * 8;  // + c0
    short* kw0 = &Klds[0][kr_ * KP + kc_ * 8];
    short* kw1 = &Klds[1][kr_ * KP + kc_ * 8];
    short* vw0 = &Vlds[0][vr_ * VP + vc_ * 8];
    short* vw1 = &Vlds[1][vr_ * VP + vc_ * 8];

    short8 rk, rv;   // staged regs for the next tile

#define LOADR(c0_)                                                             \
    rk = *(const short8*)(kgbase + (size_t)((c0_) + kr_) * D);                 \
    rv = *(const short8*)(vgbase + (c0_));

#define DSW0  { *(short8*)kw0 = rk; *(short8*)vw0 = rv; }
#define DSW1  { *(short8*)kw1 = rk; *(short8*)vw1 = rv; }

    const float2* ccp = (const float2*)ccl;

#define COMPUTE_TILE(B, lo)                                                    \
    {                                                                          \
        const short* kb = &Klds[B][0];                                         \
        const short* vb = &Vlds[B][0];                                         \
        short8 k00 = *(const short8*)(kb + l15 * KP + quad * 8);               \
        short8 k01 = *(const short8*)(kb + l15 * KP + 32 + quad * 8);          \
        short8 k10 = *(const short8*)(kb + (16 + l15) * KP + quad * 8);        \
        short8 k11 = *(const short8*)(kb + (16 + l15) * KP + 32 + quad * 8);   \
        short8 v0 = *(const short8*)(vb + l15 * VP + quad * 8);                \
        short8 v1 = *(const short8*)(vb + (16 + l15) * VP + quad * 8);         \
        short8 v2 = *(const short8*)(vb + (32 + l15) * VP + quad * 8);         \
        short8 v3 = *(const short8*)(vb + (48 + l15) * VP + quad * 8);         \
        float4v s0 = {0,0,0,0}, s1 = {0,0,0,0};                                \
        s0 = __builtin_amdgcn_mfma_f32_16x16x32_bf16(k00, qa0, s0, 0, 0, 0);   \
        s0 = __builtin_amdgcn_mfma_f32_16x16x32_bf16(k01, qa1, s0, 0, 0, 0);   \
        s1 = __builtin_amdgcn_mfma_f32_16x16x32_bf16(k10, qa0, s1, 0, 0, 0);   \
        s1 = __builtin_amdgcn_mfma_f32_16x16x32_bf16(k11, qa1, s1, 0, 0, 0);   \
        float p0v[4], p1v[4];                                                  \
        _Pragma("unroll")                                                      \
        for (int r = 0; r < 4; r++) {                                          \
            float2 ca = ccp[(lo) + 4 * quad + r];                              \
            float2 cb = ccp[(lo) + 16 + 4 * quad + r];                         \
            float dxA = qx - ca.x, dyA = qy - ca.y;                            \
            float dxB = qx - cb.x, dyB = qy - cb.y;                            \
            float dA = sqrtf(dxA * dxA + dyA * dyA);                           \
            float dB = sqrtf(dxB * dxB + dyB * dyB);                           \
            p0v[r] = __expf(__fmaf_rn(s0[r], scale, __fmaf_rn(-bh, dA, -M0))); \
            p1v[r] = __expf(__fmaf_rn(s1[r], scale, __fmaf_rn(-bh, dB, -M0))); \
            lacc += p0v[r] + p1v[r];                                           \
        }                                                                      \
        short8 pa;                                                             \
        pa[0] = f2bf(p0v[0]); pa[1] = f2bf(p0v[1]);                            \
        pa[2] = f2bf(p0v[2]); pa[3] = f2bf(p0v[3]);                            \
        pa[4] = f2bf(p1v[0]); pa[5] = f2bf(p1v[1]);                            \
        pa[6] = f2bf(p1v[2]); pa[7] = f2bf(p1v[3]);                            \
        O0 = __builtin_amdgcn_mfma_f32_16x16x32_bf16(pa, v0, O0, 0, 0, 0);     \
        O1 = __builtin_amdgcn_mfma_f32_16x16x32_bf16(pa, v1, O1, 0, 0, 0);     \
        O2 = __builtin_amdgcn_mfma_f32_16x16x32_bf16(pa, v2, O2, 0, 0, 0);     \
        O3 = __builtin_amdgcn_mfma_f32_16x16x32_bf16(pa, v3, O3, 0, 0, 0);     \
    }

    // ---- prologue: cc chunk -> LDS, tile0 -> buf0, tile1 -> regs ----
    {
        float4v ccv = *(const float4v*)(cc + (size_t)(cbase + tid * 2) * 2);
        *(float4v*)&ccl[tid * 4] = ccv;
    }
    LOADR(cbase);
    DSW0;
    LOADR(cbase + 32);
    __syncthreads();

    // ---- main loop: 16 tiles, 2x-unrolled (static buffer indices) ----
    for (int t = 0; t < NT - 2; t += 2) {
        int c0 = cbase + t * 32;
        // iter t (compute buf0): regs hold tile t+1
        DSW1;
        LOADR(c0 + 64);
        COMPUTE_TILE(0, t * 32);
        __syncthreads();
        // iter t+1 (compute buf1): regs hold tile t+2
        DSW0;
        LOADR(c0 + 96);
        COMPUTE_TILE(1, t * 32 + 32);
        __syncthreads();
    }
    // t = NT-2 (compute buf0): regs hold tile NT-1
    DSW1;
    COMPUTE_TILE(0, (NT - 2) * 32);
    __syncthreads();
    // t = NT-1 (compute buf1)
    COMPUTE_TILE(1, (NT - 1) * 32);

#undef LOADR
#undef DSW0
#undef DSW1
#undef COMPUTE_TILE

    // L reduction: sum per q=l15 across the 4 quads (lanes +-16, +-32)
    lacc += __shfl_xor(lacc, 16);
    lacc += __shfl_xor(lacc, 32);

    long base = (long)(sp * H + h) * NQ;
    // O layout: lane holds O[q = q0 + quad*4 + r][d = t*16 + l15]
    float4v Oarr[4] = {O0, O1, O2, O3};
#pragma unroll
    for (int t = 0; t < 4; t++) {
#pragma unroll
        for (int r = 0; r < 4; r++) {
            int q = q0 + quad * 4 + r;
            Opart[(base + q) * HD + t * 16 + l15] = f2bf(Oarr[t][r]);
        }
    }
    if (lane < 16)
        Lpart[base + q0 + lane] = lacc;
}

// Plain-sum combine (all splits share fixed max M0) -> bf16 Att.
__global__ __launch_bounds__(256) void attn_combine(
    const short* __restrict__ Opart, const float* __restrict__ Lpart,
    short* __restrict__ Att)
{
    int id = blockIdx.x * 256 + threadIdx.x;   // over H*NQ*HD = 2^20
    int d = id & 63;
    int q = (id >> 6) & (NQ - 1);
    int h = id >> 17;
    float L = 0.f, acc = 0.f;
#pragma unroll
    for (int s = 0; s < SPLIT; s++) {
        long b = (long)(s * H + h) * NQ + q;
        L   += Lpart[b];
        acc += bf2f(Opart[b * HD + d]);
    }
    Att[q * D + h * HD + d] = f2bf(acc / L);
}

// ---------------------------------------------------------------------------
// OLD split attention (V in LDS, coords in-kernel) — mid-size-ws fallback.
// Expects V row-major [NC][D].
// ---------------------------------------------------------------------------
__global__ __launch_bounds__(256) void attn_mfma_split(
    const short* __restrict__ Q, const short* __restrict__ K,
    const short* __restrict__ V,
    const float* __restrict__ qc, const float* __restrict__ cc,
    const float* __restrict__ log_scale, const float* __restrict__ bph,
    short* __restrict__ Opart, float* __restrict__ Lpart)
{
    __shared__ short Vt[HD][48];
    __shared__ short P[4][16][48];

    int wave = threadIdx.x >> 6, lane = threadIdx.x & 63;
    int h = blockIdx.y;
    int sp = blockIdx.z;
    int q0 = blockIdx.x * 64 + wave * 16;
    int quad = lane >> 4, l15 = lane & 15;
    int cbase = sp * CLEN;

    const float scale = 0.125f;
    float bh = __expf(log_scale[0]) * bph[h];

    const short* qp = Q + (q0 + l15) * D + h * HD + quad * 8;
    short8 qa0 = *(const short8*)(qp);
    short8 qa1 = *(const short8*)(qp + 32);

    float qx[4], qy[4];
#pragma unroll
    for (int r = 0; r < 4; r++) {
        int q = q0 + quad * 4 + r;
        qx[r] = qc[q * 2];
        qy[r] = qc[q * 2 + 1];
    }

    float lacc[4] = {0.f, 0.f, 0.f, 0.f};
    float4v O[4];
#pragma unroll
    for (int t = 0; t < 4; t++) O[t] = (float4v){0.f, 0.f, 0.f, 0.f};

    for (int c0 = cbase; c0 < cbase + CLEN; c0 += 32) {
        __syncthreads();
        {
            int c = threadIdx.x >> 3;
            int dblk = (threadIdx.x & 7) * 8;
            short8 vv = *(const short8*)(V + (c0 + c) * D + h * HD + dblk);
#pragma unroll
            for (int j = 0; j < 8; j++) Vt[dblk + j][c] = vv[j];
        }
        const short* kp0 = K + (c0 + l15) * D + h * HD + quad * 8;
        const short* kp1 = kp0 + 16 * D;
        short8 kb00 = *(const short8*)(kp0);
        short8 kb01 = *(const short8*)(kp0 + 32);
        short8 kb10 = *(const short8*)(kp1);
        short8 kb11 = *(const short8*)(kp1 + 32);
        float4v s0 = {0,0,0,0}, s1 = {0,0,0,0};
        s0 = __builtin_amdgcn_mfma_f32_16x16x32_bf16(qa0, kb00, s0, 0, 0, 0);
        s0 = __builtin_amdgcn_mfma_f32_16x16x32_bf16(qa1, kb01, s0, 0, 0, 0);
        s1 = __builtin_amdgcn_mfma_f32_16x16x32_bf16(qa0, kb10, s1, 0, 0, 0);
        s1 = __builtin_amdgcn_mfma_f32_16x16x32_bf16(qa1, kb11, s1, 0, 0, 0);

        int cA = c0 + l15, cB = cA + 16;
        float cxA = cc[cA * 2], cyA = cc[cA * 2 + 1];
        float cxB = cc[cB * 2], cyB = cc[cB * 2 + 1];
#pragma unroll
        for (int r = 0; r < 4; r++) {
            float dxA = qx[r] - cxA, dyA = qy[r] - cyA;
            float dxB = qx[r] - cxB, dyB = qy[r] - cyB;
            float p0 = __expf(s0[r] * scale - bh * sqrtf(dxA * dxA + dyA * dyA) - M0);
            float p1 = __expf(s1[r] * scale - bh * sqrtf(dxB * dxB + dyB * dyB) - M0);
            lacc[r] += p0 + p1;
            P[wave][quad * 4 + r][l15]      = f2bf(p0);
            P[wave][quad * 4 + r][16 + l15] = f2bf(p1);
        }
        __syncthreads();
        short8 pa = *(const short8*)(&P[wave][l15][quad * 8]);
#pragma unroll
        for (int t = 0; t < 4; t++) {
            short8 vb = *(const short8*)(&Vt[t * 16 + l15][quad * 8]);
            O[t] = __builtin_amdgcn_mfma_f32_16x16x32_bf16(pa, vb, O[t], 0, 0, 0);
        }
    }
#pragma unroll
    for (int r = 0; r < 4; r++) {
#pragma unroll
        for (int off = 1; off < 16; off <<= 1)
            lacc[r] += __shfl_xor(lacc[r], off);
    }
    long base = (long)(sp * H + h) * NQ;
#pragma unroll
    for (int t = 0; t < 4; t++) {
#pragma unroll
        for (int r = 0; r < 4; r++) {
            int q = q0 + quad * 4 + r;
            Opart[(base + q) * HD + t * 16 + l15] = f2bf(O[t][r]);
        }
    }
    if (l15 == 0) {
#pragma unroll
        for (int r = 0; r < 4; r++)
            Lpart[base + q0 + quad * 4 + r] = lacc[r];
    }
}

// ---------------------------------------------------------------------------
// Fallback single-pass attention (exact online softmax) if ws is too small.
// ---------------------------------------------------------------------------
__global__ __launch_bounds__(256) void attn_mfma(
    const short* __restrict__ Q, const short* __restrict__ K,
    const short* __restrict__ V,
    const float* __restrict__ qc, const float* __restrict__ cc,
    const float* __restrict__ log_scale, const float* __restrict__ bph,
    short* __restrict__ out)
{
    __shared__ short Vt[HD][48];
    __shared__ short P[4][16][48];
    int wave = threadIdx.x >> 6, lane = threadIdx.x & 63;
    int h = blockIdx.y;
    int q0 = blockIdx.x * 64 + wave * 16;
    int quad = lane >> 4, l15 = lane & 15;
    const float scale = 0.125f;
    float bh = __expf(log_scale[0]) * bph[h];
    const short* qp = Q + (q0 + l15) * D + h * HD + quad * 8;
    short8 qa0 = *(const short8*)(qp);
    short8 qa1 = *(const short8*)(qp + 32);
    float qx[4], qy[4];
#pragma unroll
    for (int r = 0; r < 4; r++) {
        int q = q0 + quad * 4 + r;
        qx[r] = qc[q * 2]; qy[r] = qc[q * 2 + 1];
    }
    float m[4], l[4];
    float4v O[4];
#pragma unroll
    for (int r = 0; r < 4; r++) { m[r] = -1e30f; l[r] = 0.f; }
#pragma unroll
    for (int t = 0; t < 4; t++) O[t] = (float4v){0.f, 0.f, 0.f, 0.f};
    for (int c0 = 0; c0 < NC; c0 += 32) {
        __syncthreads();
        {
            int c = threadIdx.x >> 3;
            int dblk = (threadIdx.x & 7) * 8;
            short8 vv = *(const short8*)(V + (c0 + c) * D + h * HD + dblk);
#pragma unroll
            for (int j = 0; j < 8; j++) Vt[dblk + j][c] = vv[j];
        }
        const short* kp0 = K + (c0 + l15) * D + h * HD + quad * 8;
        const short* kp1 = kp0 + 16 * D;
        short8 kb00 = *(const short8*)(kp0);
        short8 kb01 = *(const short8*)(kp0 + 32);
        short8 kb10 = *(const short8*)(kp1);
        short8 kb11 = *(const short8*)(kp1 + 32);
        float4v s0 = {0,0,0,0}, s1 = {0,0,0,0};
        s0 = __builtin_amdgcn_mfma_f32_16x16x32_bf16(qa0, kb00, s0, 0, 0, 0);
        s0 = __builtin_amdgcn_mfma_f32_16x16x32_bf16(qa1, kb01, s0, 0, 0, 0);
        s1 = __builtin_amdgcn_mfma_f32_16x16x32_bf16(qa0, kb10, s1, 0, 0, 0);
        s1 = __builtin_amdgcn_mfma_f32_16x16x32_bf16(qa1, kb11, s1, 0, 0, 0);
        int cA = c0 + l15, cB = cA + 16;
        float cxA = cc[cA * 2], cyA = cc[cA * 2 + 1];
        float cxB = cc[cB * 2], cyB = cc[cB * 2 + 1];
#pragma unroll
        for (int r = 0; r < 4; r++) {
            float dxA = qx[r] - cxA, dyA = qy[r] - cyA;
            float dxB = qx[r] - cxB, dyB = qy[r] - cyB;
            float v0 = s0[r] * scale - bh * sqrtf(dxA * dxA + dyA * dyA);
            float v1 = s1[r] * scale - bh * sqrtf(dxB * dxB + dyB * dyB);
            float mx = fmaxf(v0, v1);
#pragma unroll
            for (int off = 1; off < 16; off <<= 1) mx = fmaxf(mx, __shfl_xor(mx, off));
            float mnew = fmaxf(m[r], mx);
            float alpha = __expf(m[r] - mnew);
            float p0 = __expf(v0 - mnew);
            float p1 = __expf(v1 - mnew);
            float ps = p0 + p1;
#pragma unroll
            for (int off = 1; off < 16; off <<= 1) ps += __shfl_xor(ps, off);
            l[r] = l[r] * alpha + ps;
            m[r] = mnew;
#pragma unroll
            for (int t = 0; t < 4; t++) O[t][r] *= alpha;
            P[wave][quad * 4 + r][l15]      = f2bf(p0);
            P[wave][quad * 4 + r][16 + l15] = f2bf(p1);
        }
        __syncthreads();
        short8 pa = *(const short8*)(&P[wave][l15][quad * 8]);
#pragma unroll
        for (int t = 0; t < 4; t++) {
            short8 vb = *(const short8*)(&Vt[t * 16 + l15][quad * 8]);
            O[t] = __builtin_amdgcn_mfma_f32_16x16x32_bf16(pa, vb, O[t], 0, 0, 0);
        }
    }
#pragma unroll
    for (int t = 0; t < 4; t++) {
#pragma unroll
        for (int r = 0; r < 4; r++) {
            int q = q0 + quad * 4 + r;
            out[q * D + h * HD + t * 16 + l15] = f2bf(O[t][r] / l[r]);
        }
    }
}

// ---------------------------------------------------------------------------
// Row LayerNorm: one wave per row of 512 f32, output f32.
// ---------------------------------------------------------------------------
__global__ __launch_bounds__(256) void layernorm_kernel(
    const float* __restrict__ X, const float* __restrict__ g,
    const float* __restrict__ b, float* __restrict__ out)
{
    int wave = threadIdx.x >> 6, lane = threadIdx.x & 63;
    int row = blockIdx.x * 4 + wave;
    const float* xp = X + row * D;
    float v[8];
    float s = 0.f;
#pragma unroll
    for (int i = 0; i < 8; i++) { v[i] = xp[lane + i * 64]; s += v[i]; }
#pragma unroll
    for (int off = 1; off < 64; off <<= 1) s += __shfl_xor(s, off);
    float mu = s * (1.f / D);
    float var = 0.f;
#pragma unroll
    for (int i = 0; i < 8; i++) { float d = v[i] - mu; var += d * d; }
#pragma unroll
    for (int off = 1; off < 64; off <<= 1) var += __shfl_xor(var, off);
    float rstd = rsqrtf(var * (1.f / D) + 1e-5f);
#pragma unroll
    for (int i = 0; i < 8; i++) {
        int c = lane + i * 64;
        out[row * D + c] = (v[i] - mu) * rstd * g[c] + b[c];
    }
}

extern "C" void kernel_launch(void* const* d_in, const int* in_sizes, int n_in,
                              void* d_out, int out_size, void* d_ws, size_t ws_size,
                              hipStream_t stream) {
    const float* query_repr     = (const float*)d_in[0];
    const float* context_repr   = (const float*)d_in[1];
    const float* query_coords   = (const float*)d_in[2];
    const float* context_coords = (const float*)d_in[3];
    const float* Wq = (const float*)d_in[4];
    const float* bq = (const float*)d_in[5];
    const float* Wk = (const float*)d_in[6];
    const float* bk = (const float*)d_in[7];
    const float* Wv = (const float*)d_in[8];
    const float* bv = (const float*)d_in[9];
    const float* Wo = (const float*)d_in[10];
    const float* bo = (const float*)d_in[11];
    const float* ln_g = (const float*)d_in[12];
    const float* ln_b = (const float*)d_in[13];
    const float* log_scale = (const float*)d_in[14];
    const float* bph = (const float*)d_in[15];

    short* ws = (short*)d_ws;
    short* Xq_bf = ws;                       // 1,048,576 shorts
    short* Xc_bf = Xq_bf + NQ * D;           // 2,097,152
    short* Wq_bf = Xc_bf + NC * D;           //   262,144 x4
    short* Wk_bf = Wq_bf + D * D;
    short* Wv_bf = Wk_bf + D * D;
    short* Wo_bf = Wv_bf + D * D;
    short* Qw  = Wo_bf + D * D;              // 1,048,576
    short* Kw  = Qw + NQ * D;                // 2,097,152
    short* Vw  = Kw + NC * D;                // 2,097,152 (new path: Vp [D][NC] permuted)
    short* Att = Vw + NC * D;                // 1,048,576
    float* Xf  = (float*)(Att + NQ * D);     // 1,048,576 f32
    short* Opart = (short*)(Xf + NQ * D);    // SPLIT*H*NQ*HD bf16 = 16.8 MB
    float* Lpart = (float*)(Opart + (size_t)SPLIT * H * NQ * HD);  // 0.5 MB
    size_t ws_needed_split = ((char*)(Lpart + (size_t)SPLIT * H * NQ)) - (char*)d_ws;

    // 1. cast MFMA operands to bf16
    cast_all<<<dim3(4096), 256, 0, stream>>>(
        query_repr, context_repr, Wq, Wk, Wv, Wo, Xq_bf);

    // 2. Q/K projections (MFMA, 16x64 per wave)
    gemm_bt_bias<<<dim3((NQ / 16) * 8 / 4), 256, 0, stream>>>(Xq_bf, Wq_bf, bq, Qw, NQ);
    gemm_bt_bias<<<dim3((NC / 16) * 8 / 4), 256, 0, stream>>>(Xc_bf, Wk_bf, bk, Kw, NC);

    // 3. V projection + attention
    if (ws_size >= ws_needed_split) {
        // V stored transposed+permuted [D][NC]; attention v5: swapped QK,
        // in-register P, coalesced shared LDS staging, in-kernel dist.
        gemm_bt_bias_vtp<<<dim3((NC / 16) * 8 / 4), 256, 0, stream>>>(
            Xc_bf, Wv_bf, bv, Vw, NC);
        attn_mfma_split5<<<dim3(NQ / 64, H, SPLIT), 256, 0, stream>>>(
            Qw, Kw, Vw, query_coords, context_coords, log_scale, bph,
            Opart, Lpart);
        attn_combine<<<dim3(H * NQ * HD / 256), 256, 0, stream>>>(
            Opart, Lpart, Att);
    } else {
        gemm_bt_bias<<<dim3((NC / 16) * 8 / 4), 256, 0, stream>>>(
            Xc_bf, Wv_bf, bv, Vw, NC);
        attn_mfma<<<dim3(NQ / 64, H), 256, 0, stream>>>(
            Qw, Kw, Vw, query_coords, context_coords, log_scale, bph, Att);
    }

    // 4. output projection + residual (MFMA, f32 out)
    gemm_bt_bias_res_f32<<<dim3((NQ / 16) * 8 / 4), 256, 0, stream>>>(
        Att, Wo_bf, bo, query_repr, Xf, NQ);

    // 5. LayerNorm -> f32 output
    layernorm_kernel<<<dim3(NQ / 4), 256, 0, stream>>>(Xf, ln_g, ln_b, (float*)d_out);
}

// Round 5
// 204.968 us; speedup vs baseline: 1.5390x; 1.0895x over previous
//
#include <hip/hip_runtime.h>

#define D 512
#define H 8
#define HD 64
#define NQ 2048
#define NC 4096
#define SPLIT 8
#define CLEN (NC / SPLIT)   // 512 contexts per split chunk
#define NT (CLEN / 32)      // 16 tiles per chunk
#define M0 3.0f             // fixed softmax max: scores provably < 3
#define KP2 136             // K LDS row stride (shorts): 272B, 16B-aligned
#define VP 40               // V LDS row stride (shorts): 80B, 16B-aligned

typedef __attribute__((ext_vector_type(8))) short short8;
typedef __attribute__((ext_vector_type(4))) short short4v;
typedef __attribute__((ext_vector_type(4))) float float4v;
typedef __attribute__((ext_vector_type(4))) int int4v;

__device__ inline float bf2f(short s) {
    unsigned int u = ((unsigned int)(unsigned short)s) << 16;
    return __builtin_bit_cast(float, u);
}
__device__ inline short f2bf(float f) {
    unsigned int u = __builtin_bit_cast(unsigned int, f);
    u = (u + 0x7FFF + ((u >> 16) & 1)) >> 16;   // round-to-nearest-even
    return (short)u;
}
// pack two f32 -> one dword of 2 bf16 (RNE), single HW instruction
__device__ inline int cvtpk(float a, float b) {
    int w;
    asm("v_cvt_pk_bf16_f32 %0, %1, %2" : "=v"(w) : "v"(a), "v"(b));
    return w;
}

// ---------------------------------------------------------------------------
// Cast f32 -> bf16 for the 6 MFMA-operand tensors. Grid 4096 x 256.
// ---------------------------------------------------------------------------
__global__ __launch_bounds__(256) void cast_all(
    const float* __restrict__ s0, const float* __restrict__ s1,
    const float* __restrict__ s2, const float* __restrict__ s3,
    const float* __restrict__ s4, const float* __restrict__ s5,
    short* __restrict__ dst)
{
    int i = blockIdx.x * 256 + threadIdx.x;
    const float* src; int off;
    if      (i < 262144) { src = s0; off = i; }
    else if (i < 786432) { src = s1; off = i - 262144; }
    else if (i < 851968) { src = s2; off = i - 786432; }
    else if (i < 917504) { src = s3; off = i - 851968; }
    else if (i < 983040) { src = s4; off = i - 917504; }
    else                 { src = s5; off = i - 983040; }
    float4v v = ((const float4v*)src)[off];
    short4v o;
    o.x = f2bf(v.x); o.y = f2bf(v.y); o.z = f2bf(v.z); o.w = f2bf(v.w);
    ((short4v*)dst)[i] = o;
}

// ---------------------------------------------------------------------------
// GEMM: out[M x D] = X @ W^T + bias. Wave computes 16x64 (4 n-tiles).
// ---------------------------------------------------------------------------
__global__ __launch_bounds__(256) void gemm_bt_bias(
    const short* __restrict__ X, const short* __restrict__ W,
    const float* __restrict__ bias, short* __restrict__ out, int M)
{
    int wave = threadIdx.x >> 6, lane = threadIdx.x & 63;
    int gt = blockIdx.x * 4 + wave;
    int tm = gt >> 3;
    int tg = gt & 7;
    if (tm >= (M >> 4)) return;
    int l15 = lane & 15, quad = lane >> 4;
    const short* xp = X + (tm * 16 + l15) * D + quad * 8;
    const short* wp = W + (tg * 64 + l15) * D + quad * 8;
    float4v a0 = {0,0,0,0}, a1 = {0,0,0,0}, a2 = {0,0,0,0}, a3 = {0,0,0,0};
#pragma unroll
    for (int k = 0; k < D; k += 32) {
        short8 a  = *(const short8*)(xp + k);
        short8 b0 = *(const short8*)(wp + k);
        short8 b1 = *(const short8*)(wp + 16 * D + k);
        short8 b2 = *(const short8*)(wp + 32 * D + k);
        short8 b3 = *(const short8*)(wp + 48 * D + k);
        a0 = __builtin_amdgcn_mfma_f32_16x16x32_bf16(a, b0, a0, 0, 0, 0);
        a1 = __builtin_amdgcn_mfma_f32_16x16x32_bf16(a, b1, a1, 0, 0, 0);
        a2 = __builtin_amdgcn_mfma_f32_16x16x32_bf16(a, b2, a2, 0, 0, 0);
        a3 = __builtin_amdgcn_mfma_f32_16x16x32_bf16(a, b3, a3, 0, 0, 0);
    }
    int orow = tm * 16 + quad * 4;
    float4v accs[4] = {a0, a1, a2, a3};
#pragma unroll
    for (int j = 0; j < 4; j++) {
        int col = tg * 64 + j * 16 + l15;
        float bv = bias[col];
#pragma unroll
        for (int r = 0; r < 4; r++)
            out[(orow + r) * D + col] = f2bf(accs[j][r] + bv);
    }
}

// ---------------------------------------------------------------------------
// MERGED K + V projection (shared A-fragments, one launch).
// K written row-major [NC][D]; V written transposed+PERMUTED [D][NC]
// (verified rho layout: within each 32-ctx block, ctx o=4a+r stored at
// pos (a<4 ? 8a : 8(a-4)+4)+r), matching swapped-QK P fragment k-order.
// ---------------------------------------------------------------------------
__global__ __launch_bounds__(256) void gemm_bt_bias_kv(
    const short* __restrict__ X, const short* __restrict__ Wk,
    const short* __restrict__ Wv, const float* __restrict__ bk,
    const float* __restrict__ bv, short* __restrict__ outK,
    short* __restrict__ outVT, int M)
{
    int wave = threadIdx.x >> 6, lane = threadIdx.x & 63;
    int gt = blockIdx.x * 4 + wave;
    int tm = gt >> 3;
    int tg = gt & 7;
    if (tm >= (M >> 4)) return;
    int l15 = lane & 15, quad = lane >> 4;
    const short* xp  = X  + (tm * 16 + l15) * D + quad * 8;
    const short* wkp = Wk + (tg * 64 + l15) * D + quad * 8;
    const short* wvp = Wv + (tg * 64 + l15) * D + quad * 8;
    float4v k0 = {0,0,0,0}, k1 = {0,0,0,0}, k2 = {0,0,0,0}, k3 = {0,0,0,0};
    float4v v0 = {0,0,0,0}, v1 = {0,0,0,0}, v2 = {0,0,0,0}, v3 = {0,0,0,0};
#pragma unroll
    for (int k = 0; k < D; k += 32) {
        short8 a   = *(const short8*)(xp + k);
        short8 bk0 = *(const short8*)(wkp + k);
        short8 bk1 = *(const short8*)(wkp + 16 * D + k);
        short8 bk2 = *(const short8*)(wkp + 32 * D + k);
        short8 bk3 = *(const short8*)(wkp + 48 * D + k);
        short8 bv0 = *(const short8*)(wvp + k);
        short8 bv1 = *(const short8*)(wvp + 16 * D + k);
        short8 bv2 = *(const short8*)(wvp + 32 * D + k);
        short8 bv3 = *(const short8*)(wvp + 48 * D + k);
        k0 = __builtin_amdgcn_mfma_f32_16x16x32_bf16(a, bk0, k0, 0, 0, 0);
        k1 = __builtin_amdgcn_mfma_f32_16x16x32_bf16(a, bk1, k1, 0, 0, 0);
        k2 = __builtin_amdgcn_mfma_f32_16x16x32_bf16(a, bk2, k2, 0, 0, 0);
        k3 = __builtin_amdgcn_mfma_f32_16x16x32_bf16(a, bk3, k3, 0, 0, 0);
        v0 = __builtin_amdgcn_mfma_f32_16x16x32_bf16(a, bv0, v0, 0, 0, 0);
        v1 = __builtin_amdgcn_mfma_f32_16x16x32_bf16(a, bv1, v1, 0, 0, 0);
        v2 = __builtin_amdgcn_mfma_f32_16x16x32_bf16(a, bv2, v2, 0, 0, 0);
        v3 = __builtin_amdgcn_mfma_f32_16x16x32_bf16(a, bv3, v3, 0, 0, 0);
    }
    int orow = tm * 16 + quad * 4;
    // K epilogue (row-major)
    {
        float4v accs[4] = {k0, k1, k2, k3};
#pragma unroll
        for (int j = 0; j < 4; j++) {
            int col = tg * 64 + j * 16 + l15;
            float bb = bk[col];
#pragma unroll
            for (int r = 0; r < 4; r++)
                outK[(orow + r) * D + col] = f2bf(accs[j][r] + bb);
        }
    }
    // V epilogue (transposed + rho-permuted)
    {
        int a = (orow & 31) >> 2;
        int posb = (a < 4) ? (8 * a) : (8 * (a - 4) + 4);
        int cp = (orow & ~31) + posb;
        float4v accs[4] = {v0, v1, v2, v3};
#pragma unroll
        for (int j = 0; j < 4; j++) {
            int col = tg * 64 + j * 16 + l15;
            float bb = bv[col];
            short4v o;
#pragma unroll
            for (int r = 0; r < 4; r++) o[r] = f2bf(accs[j][r] + bb);
            *(short4v*)(outVT + (size_t)col * M + cp) = o;
        }
    }
}

// Same as gemm_bt_bias but adds f32 residual and writes f32 (LayerNorm input).
__global__ __launch_bounds__(256) void gemm_bt_bias_res_f32(
    const short* __restrict__ X, const short* __restrict__ W,
    const float* __restrict__ bias, const float* __restrict__ resid,
    float* __restrict__ out, int M)
{
    int wave = threadIdx.x >> 6, lane = threadIdx.x & 63;
    int gt = blockIdx.x * 4 + wave;
    int tm = gt >> 3;
    int tg = gt & 7;
    if (tm >= (M >> 4)) return;
    int l15 = lane & 15, quad = lane >> 4;
    const short* xp = X + (tm * 16 + l15) * D + quad * 8;
    const short* wp = W + (tg * 64 + l15) * D + quad * 8;
    float4v a0 = {0,0,0,0}, a1 = {0,0,0,0}, a2 = {0,0,0,0}, a3 = {0,0,0,0};
#pragma unroll
    for (int k = 0; k < D; k += 32) {
        short8 a  = *(const short8*)(xp + k);
        short8 b0 = *(const short8*)(wp + k);
        short8 b1 = *(const short8*)(wp + 16 * D + k);
        short8 b2 = *(const short8*)(wp + 32 * D + k);
        short8 b3 = *(const short8*)(wp + 48 * D + k);
        a0 = __builtin_amdgcn_mfma_f32_16x16x32_bf16(a, b0, a0, 0, 0, 0);
        a1 = __builtin_amdgcn_mfma_f32_16x16x32_bf16(a, b1, a1, 0, 0, 0);
        a2 = __builtin_amdgcn_mfma_f32_16x16x32_bf16(a, b2, a2, 0, 0, 0);
        a3 = __builtin_amdgcn_mfma_f32_16x16x32_bf16(a, b3, a3, 0, 0, 0);
    }
    int orow = tm * 16 + quad * 4;
    float4v accs[4] = {a0, a1, a2, a3};
#pragma unroll
    for (int j = 0; j < 4; j++) {
        int col = tg * 64 + j * 16 + l15;
        float bv = bias[col];
#pragma unroll
        for (int r = 0; r < 4; r++) {
            int q = orow + r;
            out[q * D + col] = accs[j][r] + bv + resid[q * D + col];
        }
    }
}

// ---------------------------------------------------------------------------
// MFMA flash attention v6 = v5 (verified: swapped-QK in-register P, coalesced
// shared double-buffered LDS staging, in-kernel dist) + VALU-cut:
//  - HEAD PAIRING: block computes heads (2y, 2y+1) for one q-tile/c-chunk.
//    dist (sqrt etc.) computed ONCE, shared by both heads (was 8x redundant
//    across the grid; now 4x -> per-score dist cost halved). K rows for the
//    pair are contiguous 128 shorts; staging amortized over 2 heads.
//  - v_cvt_pk_bf16_f32 for the P pack (4 inst vs ~36 hand-RNE).
//  - exp2f with log2e folded into scale/bh/M0 (bare v_exp_f32, no mul).
//  - __builtin_amdgcn_sqrtf (raw v_sqrt_f32, no libm fixup).
// Block = (64 q, 2 heads, 1 chunk of 512 contexts). Grid (32, 4, 8).
// ---------------------------------------------------------------------------
__global__ __launch_bounds__(256) void attn_mfma_split6(
    const short* __restrict__ Q, const short* __restrict__ K,
    const short* __restrict__ Vp,
    const float* __restrict__ qc, const float* __restrict__ cc,
    const float* __restrict__ log_scale, const float* __restrict__ bph,
    short* __restrict__ Opart, float* __restrict__ Lpart)
{
    __shared__ __align__(16) short Klds[2][32 * KP2];   // 17408 B
    __shared__ __align__(16) short Vlds[2][128 * VP];   // 20480 B
    __shared__ __align__(16) float ccl[CLEN * 2];       //  4096 B

    int tid = threadIdx.x;
    int wave = tid >> 6, lane = tid & 63;
    int h0 = blockIdx.y * 2;            // head pair (h0, h0+1)
    int sp = blockIdx.z;
    int q0 = blockIdx.x * 64 + wave * 16;
    int quad = lane >> 4, l15 = lane & 15;
    int cbase = sp * CLEN;

    const float LOG2E = 1.4426950408889634f;
    const float escale = 0.125f * LOG2E;
    const float M0L = M0 * LOG2E;
    float ebase = __expf(log_scale[0]);
    float bh0 = ebase * bph[h0] * LOG2E;
    float bh1 = ebase * bph[h0 + 1] * LOG2E;

    // Q fragments (B-operand of swapped QK), both heads (contiguous slices)
    const short* qp = Q + (q0 + l15) * D + h0 * HD + quad * 8;
    short8 qa0_0 = *(const short8*)(qp);
    short8 qa1_0 = *(const short8*)(qp + 32);
    short8 qa0_1 = *(const short8*)(qp + 64);
    short8 qa1_1 = *(const short8*)(qp + 96);

    float qx = qc[(q0 + l15) * 2];
    float qy = qc[(q0 + l15) * 2 + 1];

    float lacc0 = 0.f, lacc1 = 0.f;
    float4v O00 = {0,0,0,0}, O01 = {0,0,0,0}, O02 = {0,0,0,0}, O03 = {0,0,0,0};
    float4v O10 = {0,0,0,0}, O11 = {0,0,0,0}, O12 = {0,0,0,0}, O13 = {0,0,0,0};

    // staging maps (256 threads, 2 slots each):
    //  K tile 32 rows x 128 shorts (16 chunks/row): slot0 (r=tid>>3, c=tid&7),
    //  slot1 (same row, c+8).  V tile 128 rows x 32 shorts (4 chunks/row):
    //  slot0 (r=tid>>2, c=tid&3), slot1 (r+64, same c).
    int kr_ = tid >> 3, kc_ = tid & 7;
    int vr_ = tid >> 2, vc_ = tid & 3;
    const short* kg  = K + (size_t)h0 * HD + kc_ * 8;            // +(c0+kr_)*D
    const short* vg0 = Vp + (size_t)(h0 * HD + vr_) * NC + vc_ * 8;       // +c0
    const short* vg1 = Vp + (size_t)(h0 * HD + 64 + vr_) * NC + vc_ * 8;  // +c0
    short* kw0a = &Klds[0][kr_ * KP2 + kc_ * 8];
    short* kw1a = &Klds[1][kr_ * KP2 + kc_ * 8];
    short* vw0a = &Vlds[0][vr_ * VP + vc_ * 8];
    short* vw0b = &Vlds[0][(64 + vr_) * VP + vc_ * 8];
    short* vw1a = &Vlds[1][vr_ * VP + vc_ * 8];
    short* vw1b = &Vlds[1][(64 + vr_) * VP + vc_ * 8];

    short8 rka, rkb, rva, rvb;   // staged regs for the next tile

#define LOADR(c0_)                                                             \
    {                                                                          \
        const short* kp_ = kg + (size_t)((c0_) + kr_) * D;                     \
        rka = *(const short8*)(kp_);                                           \
        rkb = *(const short8*)(kp_ + 64);                                      \
        rva = *(const short8*)(vg0 + (c0_));                                   \
        rvb = *(const short8*)(vg1 + (c0_));                                   \
    }

#define DSW0 { *(short8*)kw0a = rka; *(short8*)(kw0a + 64) = rkb;              \
               *(short8*)vw0a = rva; *(short8*)vw0b = rvb; }
#define DSW1 { *(short8*)kw1a = rka; *(short8*)(kw1a + 64) = rkb;              \
               *(short8*)vw1a = rva; *(short8*)vw1b = rvb; }

    const float2* ccp = (const float2*)ccl;

    // one head's QK->softmax->PV given shared dA/dB
#define HEAD(hoff, QA0, QA1, BH, LACC, OA, OB, OC, OD)                         \
    {                                                                          \
        short8 k00 = *(const short8*)(kb + l15 * KP2 + (hoff) + quad * 8);     \
        short8 k01 = *(const short8*)(kb + l15 * KP2 + (hoff) + 32 + quad * 8);\
        short8 k10 = *(const short8*)(kb + (16 + l15) * KP2 + (hoff) + quad * 8);\
        short8 k11 = *(const short8*)(kb + (16 + l15) * KP2 + (hoff) + 32 + quad * 8);\
        float4v s0 = {0,0,0,0}, s1 = {0,0,0,0};                                \
        s0 = __builtin_amdgcn_mfma_f32_16x16x32_bf16(k00, QA0, s0, 0, 0, 0);   \
        s0 = __builtin_amdgcn_mfma_f32_16x16x32_bf16(k01, QA1, s0, 0, 0, 0);   \
        s1 = __builtin_amdgcn_mfma_f32_16x16x32_bf16(k10, QA0, s1, 0, 0, 0);   \
        s1 = __builtin_amdgcn_mfma_f32_16x16x32_bf16(k11, QA1, s1, 0, 0, 0);   \
        short8 v0 = *(const short8*)(vb + ((hoff) / 64 * 64 + l15) * VP + quad * 8);       \
        short8 v1 = *(const short8*)(vb + ((hoff) / 64 * 64 + 16 + l15) * VP + quad * 8);  \
        short8 v2 = *(const short8*)(vb + ((hoff) / 64 * 64 + 32 + l15) * VP + quad * 8);  \
        short8 v3 = *(const short8*)(vb + ((hoff) / 64 * 64 + 48 + l15) * VP + quad * 8);  \
        float p00 = exp2f(__fmaf_rn(s0[0], escale, __fmaf_rn(-(BH), dA0, -M0L)));\
        float p01 = exp2f(__fmaf_rn(s0[1], escale, __fmaf_rn(-(BH), dA1, -M0L)));\
        float p02 = exp2f(__fmaf_rn(s0[2], escale, __fmaf_rn(-(BH), dA2, -M0L)));\
        float p03 = exp2f(__fmaf_rn(s0[3], escale, __fmaf_rn(-(BH), dA3, -M0L)));\
        float p10 = exp2f(__fmaf_rn(s1[0], escale, __fmaf_rn(-(BH), dB0, -M0L)));\
        float p11 = exp2f(__fmaf_rn(s1[1], escale, __fmaf_rn(-(BH), dB1, -M0L)));\
        float p12 = exp2f(__fmaf_rn(s1[2], escale, __fmaf_rn(-(BH), dB2, -M0L)));\
        float p13 = exp2f(__fmaf_rn(s1[3], escale, __fmaf_rn(-(BH), dB3, -M0L)));\
        LACC += ((p00 + p01) + (p02 + p03)) + ((p10 + p11) + (p12 + p13));     \
        int4v pw;                                                              \
        pw.x = cvtpk(p00, p01); pw.y = cvtpk(p02, p03);                        \
        pw.z = cvtpk(p10, p11); pw.w = cvtpk(p12, p13);                        \
        short8 pa = __builtin_bit_cast(short8, pw);                            \
        OA = __builtin_amdgcn_mfma_f32_16x16x32_bf16(pa, v0, OA, 0, 0, 0);     \
        OB = __builtin_amdgcn_mfma_f32_16x16x32_bf16(pa, v1, OB, 0, 0, 0);     \
        OC = __builtin_amdgcn_mfma_f32_16x16x32_bf16(pa, v2, OC, 0, 0, 0);     \
        OD = __builtin_amdgcn_mfma_f32_16x16x32_bf16(pa, v3, OD, 0, 0, 0);     \
    }

#define COMPUTE_TILE(B, lo)                                                    \
    {                                                                          \
        const short* kb = &Klds[B][0];                                         \
        const short* vb = &Vlds[B][0];                                         \
        float2 ca0 = ccp[(lo) + 4 * quad + 0], cb0 = ccp[(lo) + 16 + 4 * quad + 0];\
        float2 ca1 = ccp[(lo) + 4 * quad + 1], cb1 = ccp[(lo) + 16 + 4 * quad + 1];\
        float2 ca2 = ccp[(lo) + 4 * quad + 2], cb2 = ccp[(lo) + 16 + 4 * quad + 2];\
        float2 ca3 = ccp[(lo) + 4 * quad + 3], cb3 = ccp[(lo) + 16 + 4 * quad + 3];\
        float dx, dy;                                                          \
        dx = qx - ca0.x; dy = qy - ca0.y;                                      \
        float dA0 = __builtin_amdgcn_sqrtf(__fmaf_rn(dx, dx, dy * dy));        \
        dx = qx - ca1.x; dy = qy - ca1.y;                                      \
        float dA1 = __builtin_amdgcn_sqrtf(__fmaf_rn(dx, dx, dy * dy));        \
        dx = qx - ca2.x; dy = qy - ca2.y;                                      \
        float dA2 = __builtin_amdgcn_sqrtf(__fmaf_rn(dx, dx, dy * dy));        \
        dx = qx - ca3.x; dy = qy - ca3.y;                                      \
        float dA3 = __builtin_amdgcn_sqrtf(__fmaf_rn(dx, dx, dy * dy));        \
        dx = qx - cb0.x; dy = qy - cb0.y;                                      \
        float dB0 = __builtin_amdgcn_sqrtf(__fmaf_rn(dx, dx, dy * dy));        \
        dx = qx - cb1.x; dy = qy - cb1.y;                                      \
        float dB1 = __builtin_amdgcn_sqrtf(__fmaf_rn(dx, dx, dy * dy));        \
        dx = qx - cb2.x; dy = qy - cb2.y;                                      \
        float dB2 = __builtin_amdgcn_sqrtf(__fmaf_rn(dx, dx, dy * dy));        \
        dx = qx - cb3.x; dy = qy - cb3.y;                                      \
        float dB3 = __builtin_amdgcn_sqrtf(__fmaf_rn(dx, dx, dy * dy));        \
        HEAD(0,  qa0_0, qa1_0, bh0, lacc0, O00, O01, O02, O03)                 \
        HEAD(64, qa0_1, qa1_1, bh1, lacc1, O10, O11, O12, O13)                 \
    }

    // ---- prologue: cc chunk -> LDS, tile0 -> buf0, tile1 -> regs ----
    {
        float4v ccv = *(const float4v*)(cc + (size_t)(cbase + tid * 2) * 2);
        *(float4v*)&ccl[tid * 4] = ccv;
    }
    LOADR(cbase);
    DSW0;
    LOADR(cbase + 32);
    __syncthreads();

    // ---- main loop: 16 tiles, 2x-unrolled (static buffer indices) ----
    for (int t = 0; t < NT - 2; t += 2) {
        int c0 = cbase + t * 32;
        DSW1;
        LOADR(c0 + 64);
        COMPUTE_TILE(0, t * 32);
        __syncthreads();
        DSW0;
        LOADR(c0 + 96);
        COMPUTE_TILE(1, t * 32 + 32);
        __syncthreads();
    }
    DSW1;
    COMPUTE_TILE(0, (NT - 2) * 32);
    __syncthreads();
    COMPUTE_TILE(1, (NT - 1) * 32);

#undef LOADR
#undef DSW0
#undef DSW1
#undef HEAD
#undef COMPUTE_TILE

    // L reduction: sum per q=l15 across the 4 quads (lanes +-16, +-32)
    lacc0 += __shfl_xor(lacc0, 16);
    lacc0 += __shfl_xor(lacc0, 32);
    lacc1 += __shfl_xor(lacc1, 16);
    lacc1 += __shfl_xor(lacc1, 32);

    long base0 = (long)(sp * H + h0) * NQ;
    long base1 = base0 + NQ;
    // O layout: lane holds O[q = q0 + quad*4 + r][d = t*16 + l15]
    float4v Oarr0[4] = {O00, O01, O02, O03};
    float4v Oarr1[4] = {O10, O11, O12, O13};
#pragma unroll
    for (int t = 0; t < 4; t++) {
#pragma unroll
        for (int r = 0; r < 4; r++) {
            int q = q0 + quad * 4 + r;
            Opart[(base0 + q) * HD + t * 16 + l15] = f2bf(Oarr0[t][r]);
            Opart[(base1 + q) * HD + t * 16 + l15] = f2bf(Oarr1[t][r]);
        }
    }
    if (lane < 16) {
        Lpart[base0 + q0 + lane] = lacc0;
        Lpart[base1 + q0 + lane] = lacc1;
    }
}

// Plain-sum combine (all splits share fixed max M0) -> bf16 Att.
__global__ __launch_bounds__(256) void attn_combine(
    const short* __restrict__ Opart, const float* __restrict__ Lpart,
    short* __restrict__ Att)
{
    int id = blockIdx.x * 256 + threadIdx.x;   // over H*NQ*HD = 2^20
    int d = id & 63;
    int q = (id >> 6) & (NQ - 1);
    int h = id >> 17;
    float L = 0.f, acc = 0.f;
#pragma unroll
    for (int s = 0; s < SPLIT; s++) {
        long b = (long)(s * H + h) * NQ + q;
        L   += Lpart[b];
        acc += bf2f(Opart[b * HD + d]);
    }
    Att[q * D + h * HD + d] = f2bf(acc / L);
}

// ---------------------------------------------------------------------------
// Fallback single-pass attention (exact online softmax) if ws is too small.
// Expects V row-major [NC][D].
// ---------------------------------------------------------------------------
__global__ __launch_bounds__(256) void attn_mfma(
    const short* __restrict__ Q, const short* __restrict__ K,
    const short* __restrict__ V,
    const float* __restrict__ qc, const float* __restrict__ cc,
    const float* __restrict__ log_scale, const float* __restrict__ bph,
    short* __restrict__ out)
{
    __shared__ short Vt[HD][48];
    __shared__ short P[4][16][48];
    int wave = threadIdx.x >> 6, lane = threadIdx.x & 63;
    int h = blockIdx.y;
    int q0 = blockIdx.x * 64 + wave * 16;
    int quad = lane >> 4, l15 = lane & 15;
    const float scale = 0.125f;
    float bh = __expf(log_scale[0]) * bph[h];
    const short* qp = Q + (q0 + l15) * D + h * HD + quad * 8;
    short8 qa0 = *(const short8*)(qp);
    short8 qa1 = *(const short8*)(qp + 32);
    float qx[4], qy[4];
#pragma unroll
    for (int r = 0; r < 4; r++) {
        int q = q0 + quad * 4 + r;
        qx[r] = qc[q * 2]; qy[r] = qc[q * 2 + 1];
    }
    float m[4], l[4];
    float4v O[4];
#pragma unroll
    for (int r = 0; r < 4; r++) { m[r] = -1e30f; l[r] = 0.f; }
#pragma unroll
    for (int t = 0; t < 4; t++) O[t] = (float4v){0.f, 0.f, 0.f, 0.f};
    for (int c0 = 0; c0 < NC; c0 += 32) {
        __syncthreads();
        {
            int c = threadIdx.x >> 3;
            int dblk = (threadIdx.x & 7) * 8;
            short8 vv = *(const short8*)(V + (c0 + c) * D + h * HD + dblk);
#pragma unroll
            for (int j = 0; j < 8; j++) Vt[dblk + j][c] = vv[j];
        }
        const short* kp0 = K + (c0 + l15) * D + h * HD + quad * 8;
        const short* kp1 = kp0 + 16 * D;
        short8 kb00 = *(const short8*)(kp0);
        short8 kb01 = *(const short8*)(kp0 + 32);
        short8 kb10 = *(const short8*)(kp1);
        short8 kb11 = *(const short8*)(kp1 + 32);
        float4v s0 = {0,0,0,0}, s1 = {0,0,0,0};
        s0 = __builtin_amdgcn_mfma_f32_16x16x32_bf16(qa0, kb00, s0, 0, 0, 0);
        s0 = __builtin_amdgcn_mfma_f32_16x16x32_bf16(qa1, kb01, s0, 0, 0, 0);
        s1 = __builtin_amdgcn_mfma_f32_16x16x32_bf16(qa0, kb10, s1, 0, 0, 0);
        s1 = __builtin_amdgcn_mfma_f32_16x16x32_bf16(qa1, kb11, s1, 0, 0, 0);
        int cA = c0 + l15, cB = cA + 16;
        float cxA = cc[cA * 2], cyA = cc[cA * 2 + 1];
        float cxB = cc[cB * 2], cyB = cc[cB * 2 + 1];
#pragma unroll
        for (int r = 0; r < 4; r++) {
            float dxA = qx[r] - cxA, dyA = qy[r] - cyA;
            float dxB = qx[r] - cxB, dyB = qy[r] - cyB;
            float v0 = s0[r] * scale - bh * sqrtf(dxA * dxA + dyA * dyA);
            float v1 = s1[r] * scale - bh * sqrtf(dxB * dxB + dyB * dyB);
            float mx = fmaxf(v0, v1);
#pragma unroll
            for (int off = 1; off < 16; off <<= 1) mx = fmaxf(mx, __shfl_xor(mx, off));
            float mnew = fmaxf(m[r], mx);
            float alpha = __expf(m[r] - mnew);
            float p0 = __expf(v0 - mnew);
            float p1 = __expf(v1 - mnew);
            float ps = p0 + p1;
#pragma unroll
            for (int off = 1; off < 16; off <<= 1) ps += __shfl_xor(ps, off);
            l[r] = l[r] * alpha + ps;
            m[r] = mnew;
#pragma unroll
            for (int t = 0; t < 4; t++) O[t][r] *= alpha;
            P[wave][quad * 4 + r][l15]      = f2bf(p0);
            P[wave][quad * 4 + r][16 + l15] = f2bf(p1);
        }
        __syncthreads();
        short8 pa = *(const short8*)(&P[wave][l15][quad * 8]);
#pragma unroll
        for (int t = 0; t < 4; t++) {
            short8 vb = *(const short8*)(&Vt[t * 16 + l15][quad * 8]);
            O[t] = __builtin_amdgcn_mfma_f32_16x16x32_bf16(pa, vb, O[t], 0, 0, 0);
        }
    }
#pragma unroll
    for (int t = 0; t < 4; t++) {
#pragma unroll
        for (int r = 0; r < 4; r++) {
            int q = q0 + quad * 4 + r;
            out[q * D + h * HD + t * 16 + l15] = f2bf(O[t][r] / l[r]);
        }
    }
}

// ---------------------------------------------------------------------------
// Row LayerNorm: one wave per row of 512 f32, output f32.
// ---------------------------------------------------------------------------
__global__ __launch_bounds__(256) void layernorm_kernel(
    const float* __restrict__ X, const float* __restrict__ g,
    const float* __restrict__ b, float* __restrict__ out)
{
    int wave = threadIdx.x >> 6, lane = threadIdx.x & 63;
    int row = blockIdx.x * 4 + wave;
    const float* xp = X + row * D;
    float v[8];
    float s = 0.f;
#pragma unroll
    for (int i = 0; i < 8; i++) { v[i] = xp[lane + i * 64]; s += v[i]; }
#pragma unroll
    for (int off = 1; off < 64; off <<= 1) s += __shfl_xor(s, off);
    float mu = s * (1.f / D);
    float var = 0.f;
#pragma unroll
    for (int i = 0; i < 8; i++) { float d = v[i] - mu; var += d * d; }
#pragma unroll
    for (int off = 1; off < 64; off <<= 1) var += __shfl_xor(var, off);
    float rstd = rsqrtf(var * (1.f / D) + 1e-5f);
#pragma unroll
    for (int i = 0; i < 8; i++) {
        int c = lane + i * 64;
        out[row * D + c] = (v[i] - mu) * rstd * g[c] + b[c];
    }
}

extern "C" void kernel_launch(void* const* d_in, const int* in_sizes, int n_in,
                              void* d_out, int out_size, void* d_ws, size_t ws_size,
                              hipStream_t stream) {
    const float* query_repr     = (const float*)d_in[0];
    const float* context_repr   = (const float*)d_in[1];
    const float* query_coords   = (const float*)d_in[2];
    const float* context_coords = (const float*)d_in[3];
    const float* Wq = (const float*)d_in[4];
    const float* bq = (const float*)d_in[5];
    const float* Wk = (const float*)d_in[6];
    const float* bk = (const float*)d_in[7];
    const float* Wv = (const float*)d_in[8];
    const float* bv = (const float*)d_in[9];
    const float* Wo = (const float*)d_in[10];
    const float* bo = (const float*)d_in[11];
    const float* ln_g = (const float*)d_in[12];
    const float* ln_b = (const float*)d_in[13];
    const float* log_scale = (const float*)d_in[14];
    const float* bph = (const float*)d_in[15];

    short* ws = (short*)d_ws;
    short* Xq_bf = ws;                       // 1,048,576 shorts
    short* Xc_bf = Xq_bf + NQ * D;           // 2,097,152
    short* Wq_bf = Xc_bf + NC * D;           //   262,144 x4
    short* Wk_bf = Wq_bf + D * D;
    short* Wv_bf = Wk_bf + D * D;
    short* Wo_bf = Wv_bf + D * D;
    short* Qw  = Wo_bf + D * D;              // 1,048,576
    short* Kw  = Qw + NQ * D;                // 2,097,152
    short* Vw  = Kw + NC * D;                // 2,097,152 (Vp [D][NC] permuted)
    short* Att = Vw + NC * D;                // 1,048,576
    float* Xf  = (float*)(Att + NQ * D);     // 1,048,576 f32
    short* Opart = (short*)(Xf + NQ * D);    // SPLIT*H*NQ*HD bf16 = 16.8 MB
    float* Lpart = (float*)(Opart + (size_t)SPLIT * H * NQ * HD);  // 0.5 MB
    size_t ws_needed_split = ((char*)(Lpart + (size_t)SPLIT * H * NQ)) - (char*)d_ws;

    // 1. cast MFMA operands to bf16
    cast_all<<<dim3(4096), 256, 0, stream>>>(
        query_repr, context_repr, Wq, Wk, Wv, Wo, Xq_bf);

    // 2. Q projection (MFMA, 16x64 per wave)
    gemm_bt_bias<<<dim3((NQ / 16) * 8 / 4), 256, 0, stream>>>(Xq_bf, Wq_bf, bq, Qw, NQ);

    // 3. K+V projections + attention
    if (ws_size >= ws_needed_split) {
        // merged K/V projection (shared A-frags); V transposed+permuted.
        gemm_bt_bias_kv<<<dim3((NC / 16) * 8 / 4), 256, 0, stream>>>(
            Xc_bf, Wk_bf, Wv_bf, bk, bv, Kw, Vw, NC);
        attn_mfma_split6<<<dim3(NQ / 64, H / 2, SPLIT), 256, 0, stream>>>(
            Qw, Kw, Vw, query_coords, context_coords, log_scale, bph,
            Opart, Lpart);
        attn_combine<<<dim3(H * NQ * HD / 256), 256, 0, stream>>>(
            Opart, Lpart, Att);
    } else {
        gemm_bt_bias<<<dim3((NC / 16) * 8 / 4), 256, 0, stream>>>(
            Xc_bf, Wk_bf, bk, Kw, NC);
        gemm_bt_bias<<<dim3((NC / 16) * 8 / 4), 256, 0, stream>>>(
            Xc_bf, Wv_bf, bv, Vw, NC);
        attn_mfma<<<dim3(NQ / 64, H), 256, 0, stream>>>(
            Qw, Kw, Vw, query_coords, context_coords, log_scale, bph, Att);
    }

    // 4. output projection + residual (MFMA, f32 out)
    gemm_bt_bias_res_f32<<<dim3((NQ / 16) * 8 / 4), 256, 0, stream>>>(
        Att, Wo_bf, bo, query_repr, Xf, NQ);

    // 5. LayerNorm -> f32 output
    layernorm_kernel<<<dim3(NQ / 4), 256, 0, stream>>>(Xf, ln_g, ln_b, (float*)d_out);
}

// Round 8
// 200.353 us; speedup vs baseline: 1.5745x; 1.0230x over previous
//
#include <hip/hip_runtime.h>

#define D 512
#define H 8
#define HD 64
#define NQ 2048
#define NC 4096
#define SPLIT 8
#define CLEN (NC / SPLIT)   // 512 contexts per split chunk
#define NT (CLEN / 32)      // 16 tiles per chunk
#define M0 3.0f             // fixed softmax max: scores provably < 3
#define KP2 136             // K LDS row stride (shorts): 272B, 16B-aligned
#define VP 40               // V LDS row stride (shorts): 80B, 16B-aligned

typedef __attribute__((ext_vector_type(8))) short short8;
typedef __attribute__((ext_vector_type(4))) short short4v;
typedef __attribute__((ext_vector_type(4))) float float4v;
typedef __attribute__((ext_vector_type(4))) int int4v;

__device__ inline float bf2f(short s) {
    unsigned int u = ((unsigned int)(unsigned short)s) << 16;
    return __builtin_bit_cast(float, u);
}
__device__ inline short f2bf(float f) {
    unsigned int u = __builtin_bit_cast(unsigned int, f);
    u = (u + 0x7FFF + ((u >> 16) & 1)) >> 16;   // round-to-nearest-even
    return (short)u;
}
// pack two f32 -> one dword of 2 bf16 (RNE), single HW instruction
__device__ inline int cvtpk(float a, float b) {
    int w;
    asm("v_cvt_pk_bf16_f32 %0, %1, %2" : "=v"(w) : "v"(a), "v"(b));
    return w;
}

// ---------------------------------------------------------------------------
// Cast f32 -> bf16 for the 6 MFMA-operand tensors. Grid 4096 x 256.
// ---------------------------------------------------------------------------
__global__ __launch_bounds__(256) void cast_all(
    const float* __restrict__ s0, const float* __restrict__ s1,
    const float* __restrict__ s2, const float* __restrict__ s3,
    const float* __restrict__ s4, const float* __restrict__ s5,
    short* __restrict__ dst)
{
    int i = blockIdx.x * 256 + threadIdx.x;
    const float* src; int off;
    if      (i < 262144) { src = s0; off = i; }
    else if (i < 786432) { src = s1; off = i - 262144; }
    else if (i < 851968) { src = s2; off = i - 786432; }
    else if (i < 917504) { src = s3; off = i - 851968; }
    else if (i < 983040) { src = s4; off = i - 917504; }
    else                 { src = s5; off = i - 983040; }
    float4v v = ((const float4v*)src)[off];
    short4v o;
    o.x = f2bf(v.x); o.y = f2bf(v.y); o.z = f2bf(v.z); o.w = f2bf(v.w);
    ((short4v*)dst)[i] = o;
}

// ---------------------------------------------------------------------------
// GEMM: out[M x D] = X @ W^T + bias. Wave computes 16x64 (4 n-tiles).
// ---------------------------------------------------------------------------
__global__ __launch_bounds__(256) void gemm_bt_bias(
    const short* __restrict__ X, const short* __restrict__ W,
    const float* __restrict__ bias, short* __restrict__ out, int M)
{
    int wave = threadIdx.x >> 6, lane = threadIdx.x & 63;
    int gt = blockIdx.x * 4 + wave;
    int tm = gt >> 3;
    int tg = gt & 7;
    if (tm >= (M >> 4)) return;
    int l15 = lane & 15, quad = lane >> 4;
    const short* xp = X + (tm * 16 + l15) * D + quad * 8;
    const short* wp = W + (tg * 64 + l15) * D + quad * 8;
    float4v a0 = {0,0,0,0}, a1 = {0,0,0,0}, a2 = {0,0,0,0}, a3 = {0,0,0,0};
#pragma unroll
    for (int k = 0; k < D; k += 32) {
        short8 a  = *(const short8*)(xp + k);
        short8 b0 = *(const short8*)(wp + k);
        short8 b1 = *(const short8*)(wp + 16 * D + k);
        short8 b2 = *(const short8*)(wp + 32 * D + k);
        short8 b3 = *(const short8*)(wp + 48 * D + k);
        a0 = __builtin_amdgcn_mfma_f32_16x16x32_bf16(a, b0, a0, 0, 0, 0);
        a1 = __builtin_amdgcn_mfma_f32_16x16x32_bf16(a, b1, a1, 0, 0, 0);
        a2 = __builtin_amdgcn_mfma_f32_16x16x32_bf16(a, b2, a2, 0, 0, 0);
        a3 = __builtin_amdgcn_mfma_f32_16x16x32_bf16(a, b3, a3, 0, 0, 0);
    }
    int orow = tm * 16 + quad * 4;
    float4v accs[4] = {a0, a1, a2, a3};
#pragma unroll
    for (int j = 0; j < 4; j++) {
        int col = tg * 64 + j * 16 + l15;
        float bv = bias[col];
#pragma unroll
        for (int r = 0; r < 4; r++)
            out[(orow + r) * D + col] = f2bf(accs[j][r] + bv);
    }
}

// ---------------------------------------------------------------------------
// MERGED K + V projection (shared A-fragments, one launch).
// K written row-major [NC][D]; V written transposed+PERMUTED [D][NC]
// (verified rho layout: within each 32-ctx block, ctx o=4a+r stored at
// pos (a<4 ? 8a : 8(a-4)+4)+r), matching swapped-QK P fragment k-order.
// ---------------------------------------------------------------------------
__global__ __launch_bounds__(256) void gemm_bt_bias_kv(
    const short* __restrict__ X, const short* __restrict__ Wk,
    const short* __restrict__ Wv, const float* __restrict__ bk,
    const float* __restrict__ bv, short* __restrict__ outK,
    short* __restrict__ outVT, int M)
{
    int wave = threadIdx.x >> 6, lane = threadIdx.x & 63;
    int gt = blockIdx.x * 4 + wave;
    int tm = gt >> 3;
    int tg = gt & 7;
    if (tm >= (M >> 4)) return;
    int l15 = lane & 15, quad = lane >> 4;
    const short* xp  = X  + (tm * 16 + l15) * D + quad * 8;
    const short* wkp = Wk + (tg * 64 + l15) * D + quad * 8;
    const short* wvp = Wv + (tg * 64 + l15) * D + quad * 8;
    float4v k0 = {0,0,0,0}, k1 = {0,0,0,0}, k2 = {0,0,0,0}, k3 = {0,0,0,0};
    float4v v0 = {0,0,0,0}, v1 = {0,0,0,0}, v2 = {0,0,0,0}, v3 = {0,0,0,0};
#pragma unroll
    for (int k = 0; k < D; k += 32) {
        short8 a   = *(const short8*)(xp + k);
        short8 bk0 = *(const short8*)(wkp + k);
        short8 bk1 = *(const short8*)(wkp + 16 * D + k);
        short8 bk2 = *(const short8*)(wkp + 32 * D + k);
        short8 bk3 = *(const short8*)(wkp + 48 * D + k);
        short8 bv0 = *(const short8*)(wvp + k);
        short8 bv1 = *(const short8*)(wvp + 16 * D + k);
        short8 bv2 = *(const short8*)(wvp + 32 * D + k);
        short8 bv3 = *(const short8*)(wvp + 48 * D + k);
        k0 = __builtin_amdgcn_mfma_f32_16x16x32_bf16(a, bk0, k0, 0, 0, 0);
        k1 = __builtin_amdgcn_mfma_f32_16x16x32_bf16(a, bk1, k1, 0, 0, 0);
        k2 = __builtin_amdgcn_mfma_f32_16x16x32_bf16(a, bk2, k2, 0, 0, 0);
        k3 = __builtin_amdgcn_mfma_f32_16x16x32_bf16(a, bk3, k3, 0, 0, 0);
        v0 = __builtin_amdgcn_mfma_f32_16x16x32_bf16(a, bv0, v0, 0, 0, 0);
        v1 = __builtin_amdgcn_mfma_f32_16x16x32_bf16(a, bv1, v1, 0, 0, 0);
        v2 = __builtin_amdgcn_mfma_f32_16x16x32_bf16(a, bv2, v2, 0, 0, 0);
        v3 = __builtin_amdgcn_mfma_f32_16x16x32_bf16(a, bv3, v3, 0, 0, 0);
    }
    int orow = tm * 16 + quad * 4;
    // K epilogue (row-major)
    {
        float4v accs[4] = {k0, k1, k2, k3};
#pragma unroll
        for (int j = 0; j < 4; j++) {
            int col = tg * 64 + j * 16 + l15;
            float bb = bk[col];
#pragma unroll
            for (int r = 0; r < 4; r++)
                outK[(orow + r) * D + col] = f2bf(accs[j][r] + bb);
        }
    }
    // V epilogue (transposed + rho-permuted)
    {
        int a = (orow & 31) >> 2;
        int posb = (a < 4) ? (8 * a) : (8 * (a - 4) + 4);
        int cp = (orow & ~31) + posb;
        float4v accs[4] = {v0, v1, v2, v3};
#pragma unroll
        for (int j = 0; j < 4; j++) {
            int col = tg * 64 + j * 16 + l15;
            float bb = bv[col];
            short4v o;
#pragma unroll
            for (int r = 0; r < 4; r++) o[r] = f2bf(accs[j][r] + bb);
            *(short4v*)(outVT + (size_t)col * M + cp) = o;
        }
    }
}

// Same as gemm_bt_bias but adds f32 residual and writes f32 (LayerNorm input).
__global__ __launch_bounds__(256) void gemm_bt_bias_res_f32(
    const short* __restrict__ X, const short* __restrict__ W,
    const float* __restrict__ bias, const float* __restrict__ resid,
    float* __restrict__ out, int M)
{
    int wave = threadIdx.x >> 6, lane = threadIdx.x & 63;
    int gt = blockIdx.x * 4 + wave;
    int tm = gt >> 3;
    int tg = gt & 7;
    if (tm >= (M >> 4)) return;
    int l15 = lane & 15, quad = lane >> 4;
    const short* xp = X + (tm * 16 + l15) * D + quad * 8;
    const short* wp = W + (tg * 64 + l15) * D + quad * 8;
    float4v a0 = {0,0,0,0}, a1 = {0,0,0,0}, a2 = {0,0,0,0}, a3 = {0,0,0,0};
#pragma unroll
    for (int k = 0; k < D; k += 32) {
        short8 a  = *(const short8*)(xp + k);
        short8 b0 = *(const short8*)(wp + k);
        short8 b1 = *(const short8*)(wp + 16 * D + k);
        short8 b2 = *(const short8*)(wp + 32 * D + k);
        short8 b3 = *(const short8*)(wp + 48 * D + k);
        a0 = __builtin_amdgcn_mfma_f32_16x16x32_bf16(a, b0, a0, 0, 0, 0);
        a1 = __builtin_amdgcn_mfma_f32_16x16x32_bf16(a, b1, a1, 0, 0, 0);
        a2 = __builtin_amdgcn_mfma_f32_16x16x32_bf16(a, b2, a2, 0, 0, 0);
        a3 = __builtin_amdgcn_mfma_f32_16x16x32_bf16(a, b3, a3, 0, 0, 0);
    }
    int orow = tm * 16 + quad * 4;
    float4v accs[4] = {a0, a1, a2, a3};
#pragma unroll
    for (int j = 0; j < 4; j++) {
        int col = tg * 64 + j * 16 + l15;
        float bv = bias[col];
#pragma unroll
        for (int r = 0; r < 4; r++) {
            int q = orow + r;
            out[q * D + col] = accs[j][r] + bv + resid[q * D + col];
        }
    }
}

// ---------------------------------------------------------------------------
// MFMA flash attention v9 = v6 (PASSED at 205us: swapped-QK in-register P,
// head pairing, coalesced shared double-buffered LDS staging, cvt_pk, exp2,
// M0 fixed-max, cc staged in LDS — the proven data path) + ONE change:
//  - ccl HALVED to 256 contexts (2048 B) with a midpoint refill at tile 8
//    (wave-uniform branch; refill is race-free: last phase-A read precedes
//    the t=6 iteration's trailing barrier). LDS 41984 -> 39936 B
//    => 4 blocks/CU; grid 1024 = exactly 4/CU, zero tail.
// NOTE: cc-from-global (v7/v8) produced NaN twice — do not reintroduce.
// Block = (64 q, 2 heads, 1 chunk of 512 contexts). Grid (32, 4, 8).
// ---------------------------------------------------------------------------
__global__ __launch_bounds__(256) void attn_mfma_split9(
    const short* __restrict__ Q, const short* __restrict__ K,
    const short* __restrict__ Vp,
    const float* __restrict__ qc, const float* __restrict__ cc,
    const float* __restrict__ log_scale, const float* __restrict__ bph,
    short* __restrict__ Opart, float* __restrict__ Lpart)
{
    __shared__ __align__(16) short Klds[2][32 * KP2];   // 17408 B
    __shared__ __align__(16) short Vlds[2][128 * VP];   // 20480 B
    __shared__ __align__(16) float ccl[512];            //  2048 B (256 ctx)

    int tid = threadIdx.x;
    int wave = tid >> 6, lane = tid & 63;
    int h0 = blockIdx.y * 2;            // head pair (h0, h0+1)
    int sp = blockIdx.z;
    int q0 = blockIdx.x * 64 + wave * 16;
    int quad = lane >> 4, l15 = lane & 15;
    int cbase = sp * CLEN;

    const float LOG2E = 1.4426950408889634f;
    const float escale = 0.125f * LOG2E;
    const float M0L = M0 * LOG2E;
    float ebase = __expf(log_scale[0]);
    float bh0 = ebase * bph[h0] * LOG2E;
    float bh1 = ebase * bph[h0 + 1] * LOG2E;

    // Q fragments (B-operand of swapped QK), both heads (contiguous slices)
    const short* qp = Q + (q0 + l15) * D + h0 * HD + quad * 8;
    short8 qa0_0 = *(const short8*)(qp);
    short8 qa1_0 = *(const short8*)(qp + 32);
    short8 qa0_1 = *(const short8*)(qp + 64);
    short8 qa1_1 = *(const short8*)(qp + 96);

    float qx = qc[(q0 + l15) * 2];
    float qy = qc[(q0 + l15) * 2 + 1];

    float lacc0 = 0.f, lacc1 = 0.f;
    float4v O00 = {0,0,0,0}, O01 = {0,0,0,0}, O02 = {0,0,0,0}, O03 = {0,0,0,0};
    float4v O10 = {0,0,0,0}, O11 = {0,0,0,0}, O12 = {0,0,0,0}, O13 = {0,0,0,0};

    // staging maps (256 threads, 2 slots each):
    //  K tile 32 rows x 128 shorts: slot0 (r=tid>>3, c=tid&7), slot1 (c+8).
    //  V tile 128 rows x 32 shorts: slot0 (r=tid>>2, c=tid&3), slot1 (r+64).
    int kr_ = tid >> 3, kc_ = tid & 7;
    int vr_ = tid >> 2, vc_ = tid & 3;
    const short* kg  = K + (size_t)h0 * HD + kc_ * 8;            // +(c0+kr_)*D
    const short* vg0 = Vp + (size_t)(h0 * HD + vr_) * NC + vc_ * 8;       // +c0
    const short* vg1 = Vp + (size_t)(h0 * HD + 64 + vr_) * NC + vc_ * 8;  // +c0
    short* kw0a = &Klds[0][kr_ * KP2 + kc_ * 8];
    short* kw1a = &Klds[1][kr_ * KP2 + kc_ * 8];
    short* vw0a = &Vlds[0][vr_ * VP + vc_ * 8];
    short* vw0b = &Vlds[0][(64 + vr_) * VP + vc_ * 8];
    short* vw1a = &Vlds[1][vr_ * VP + vc_ * 8];
    short* vw1b = &Vlds[1][(64 + vr_) * VP + vc_ * 8];

    short8 rka, rkb, rva, rvb;   // staged regs for the next tile

#define LOADR(c0_)                                                             \
    {                                                                          \
        const short* kp_ = kg + (size_t)((c0_) + kr_) * D;                     \
        rka = *(const short8*)(kp_);                                           \
        rkb = *(const short8*)(kp_ + 64);                                      \
        rva = *(const short8*)(vg0 + (c0_));                                   \
        rvb = *(const short8*)(vg1 + (c0_));                                   \
    }

#define DSW0 { *(short8*)kw0a = rka; *(short8*)(kw0a + 64) = rkb;              \
               *(short8*)vw0a = rva; *(short8*)vw0b = rvb; }
#define DSW1 { *(short8*)kw1a = rka; *(short8*)(kw1a + 64) = rkb;              \
               *(short8*)vw1a = rva; *(short8*)vw1b = rvb; }

    const float2* ccp = (const float2*)ccl;

    // one head's QK->softmax->PV given shared dA/dB (v6 numerics: escale+M0)
#define HEAD(hoff, QA0, QA1, BH, LACC, OA, OB, OC, OD)                         \
    {                                                                          \
        short8 k00 = *(const short8*)(kb + l15 * KP2 + (hoff) + quad * 8);     \
        short8 k01 = *(const short8*)(kb + l15 * KP2 + (hoff) + 32 + quad * 8);\
        short8 k10 = *(const short8*)(kb + (16 + l15) * KP2 + (hoff) + quad * 8);\
        short8 k11 = *(const short8*)(kb + (16 + l15) * KP2 + (hoff) + 32 + quad * 8);\
        float4v s0 = {0,0,0,0}, s1 = {0,0,0,0};                                \
        s0 = __builtin_amdgcn_mfma_f32_16x16x32_bf16(k00, QA0, s0, 0, 0, 0);   \
        s0 = __builtin_amdgcn_mfma_f32_16x16x32_bf16(k01, QA1, s0, 0, 0, 0);   \
        s1 = __builtin_amdgcn_mfma_f32_16x16x32_bf16(k10, QA0, s1, 0, 0, 0);   \
        s1 = __builtin_amdgcn_mfma_f32_16x16x32_bf16(k11, QA1, s1, 0, 0, 0);   \
        short8 v0 = *(const short8*)(vb + ((hoff) / 64 * 64 + l15) * VP + quad * 8);       \
        short8 v1 = *(const short8*)(vb + ((hoff) / 64 * 64 + 16 + l15) * VP + quad * 8);  \
        short8 v2 = *(const short8*)(vb + ((hoff) / 64 * 64 + 32 + l15) * VP + quad * 8);  \
        short8 v3 = *(const short8*)(vb + ((hoff) / 64 * 64 + 48 + l15) * VP + quad * 8);  \
        float p00 = exp2f(__fmaf_rn(s0[0], escale, __fmaf_rn(-(BH), dA0, -M0L)));\
        float p01 = exp2f(__fmaf_rn(s0[1], escale, __fmaf_rn(-(BH), dA1, -M0L)));\
        float p02 = exp2f(__fmaf_rn(s0[2], escale, __fmaf_rn(-(BH), dA2, -M0L)));\
        float p03 = exp2f(__fmaf_rn(s0[3], escale, __fmaf_rn(-(BH), dA3, -M0L)));\
        float p10 = exp2f(__fmaf_rn(s1[0], escale, __fmaf_rn(-(BH), dB0, -M0L)));\
        float p11 = exp2f(__fmaf_rn(s1[1], escale, __fmaf_rn(-(BH), dB1, -M0L)));\
        float p12 = exp2f(__fmaf_rn(s1[2], escale, __fmaf_rn(-(BH), dB2, -M0L)));\
        float p13 = exp2f(__fmaf_rn(s1[3], escale, __fmaf_rn(-(BH), dB3, -M0L)));\
        LACC += ((p00 + p01) + (p02 + p03)) + ((p10 + p11) + (p12 + p13));     \
        int4v pw;                                                              \
        pw.x = cvtpk(p00, p01); pw.y = cvtpk(p02, p03);                        \
        pw.z = cvtpk(p10, p11); pw.w = cvtpk(p12, p13);                        \
        short8 pa = __builtin_bit_cast(short8, pw);                            \
        OA = __builtin_amdgcn_mfma_f32_16x16x32_bf16(pa, v0, OA, 0, 0, 0);     \
        OB = __builtin_amdgcn_mfma_f32_16x16x32_bf16(pa, v1, OB, 0, 0, 0);     \
        OC = __builtin_amdgcn_mfma_f32_16x16x32_bf16(pa, v2, OC, 0, 0, 0);     \
        OD = __builtin_amdgcn_mfma_f32_16x16x32_bf16(pa, v3, OD, 0, 0, 0);     \
    }

    // lo = context offset RELATIVE to the current ccl phase (0..224)
#define COMPUTE_TILE(B, lo)                                                    \
    {                                                                          \
        const short* kb = &Klds[B][0];                                         \
        const short* vb = &Vlds[B][0];                                         \
        float2 ca0 = ccp[(lo) + 4 * quad + 0], cb0 = ccp[(lo) + 16 + 4 * quad + 0];\
        float2 ca1 = ccp[(lo) + 4 * quad + 1], cb1 = ccp[(lo) + 16 + 4 * quad + 1];\
        float2 ca2 = ccp[(lo) + 4 * quad + 2], cb2 = ccp[(lo) + 16 + 4 * quad + 2];\
        float2 ca3 = ccp[(lo) + 4 * quad + 3], cb3 = ccp[(lo) + 16 + 4 * quad + 3];\
        float dx, dy;                                                          \
        dx = qx - ca0.x; dy = qy - ca0.y;                                      \
        float dA0 = __builtin_amdgcn_sqrtf(__fmaf_rn(dx, dx, dy * dy));        \
        dx = qx - ca1.x; dy = qy - ca1.y;                                      \
        float dA1 = __builtin_amdgcn_sqrtf(__fmaf_rn(dx, dx, dy * dy));        \
        dx = qx - ca2.x; dy = qy - ca2.y;                                      \
        float dA2 = __builtin_amdgcn_sqrtf(__fmaf_rn(dx, dx, dy * dy));        \
        dx = qx - ca3.x; dy = qy - ca3.y;                                      \
        float dA3 = __builtin_amdgcn_sqrtf(__fmaf_rn(dx, dx, dy * dy));        \
        dx = qx - cb0.x; dy = qy - cb0.y;                                      \
        float dB0 = __builtin_amdgcn_sqrtf(__fmaf_rn(dx, dx, dy * dy));        \
        dx = qx - cb1.x; dy = qy - cb1.y;                                      \
        float dB1 = __builtin_amdgcn_sqrtf(__fmaf_rn(dx, dx, dy * dy));        \
        dx = qx - cb2.x; dy = qy - cb2.y;                                      \
        float dB2 = __builtin_amdgcn_sqrtf(__fmaf_rn(dx, dx, dy * dy));        \
        dx = qx - cb3.x; dy = qy - cb3.y;                                      \
        float dB3 = __builtin_amdgcn_sqrtf(__fmaf_rn(dx, dx, dy * dy));        \
        HEAD(0,  qa0_0, qa1_0, bh0, lacc0, O00, O01, O02, O03)                 \
        HEAD(64, qa0_1, qa1_1, bh1, lacc1, O10, O11, O12, O13)                 \
    }

    // ---- prologue: cc phase A (256 ctx) -> LDS, tile0 -> buf0, tile1 -> regs
    ((float2*)ccl)[tid] = ((const float2*)cc)[cbase + tid];
    LOADR(cbase);
    DSW0;
    LOADR(cbase + 32);
    __syncthreads();

    // ---- main loop: 16 tiles, 2x-unrolled (static buffer indices) ----
    // ccl phase A serves tiles 0..7 (rel 0..224); refill at t==8 for 8..15.
    for (int t = 0; t < NT - 2; t += 2) {
        int c0 = cbase + t * 32;
        if (t == 8) {
            // race-free: all phase-A reads precede the t=6 trailing barrier
            ((float2*)ccl)[tid] = ((const float2*)cc)[cbase + 256 + tid];
            __syncthreads();
        }
        DSW1;
        LOADR(c0 + 64);
        COMPUTE_TILE(0, (t & 7) * 32);
        __syncthreads();
        DSW0;
        LOADR(c0 + 96);
        COMPUTE_TILE(1, (t & 7) * 32 + 32);
        __syncthreads();
    }
    DSW1;
    COMPUTE_TILE(0, 192);   // tile 14, rel (14-8)*32
    __syncthreads();
    COMPUTE_TILE(1, 224);   // tile 15, rel (15-8)*32

#undef LOADR
#undef DSW0
#undef DSW1
#undef HEAD
#undef COMPUTE_TILE

    // L reduction: sum per q=l15 across the 4 quads (lanes +-16, +-32)
    lacc0 += __shfl_xor(lacc0, 16);
    lacc0 += __shfl_xor(lacc0, 32);
    lacc1 += __shfl_xor(lacc1, 16);
    lacc1 += __shfl_xor(lacc1, 32);

    long base0 = (long)(sp * H + h0) * NQ;
    long base1 = base0 + NQ;
    // O layout: lane holds O[q = q0 + quad*4 + r][d = t*16 + l15]
    float4v Oarr0[4] = {O00, O01, O02, O03};
    float4v Oarr1[4] = {O10, O11, O12, O13};
#pragma unroll
    for (int t = 0; t < 4; t++) {
#pragma unroll
        for (int r = 0; r < 4; r++) {
            int q = q0 + quad * 4 + r;
            Opart[(base0 + q) * HD + t * 16 + l15] = f2bf(Oarr0[t][r]);
            Opart[(base1 + q) * HD + t * 16 + l15] = f2bf(Oarr1[t][r]);
        }
    }
    if (lane < 16) {
        Lpart[base0 + q0 + lane] = lacc0;
        Lpart[base1 + q0 + lane] = lacc1;
    }
}

// Plain-sum combine (all splits share fixed max M0) -> bf16 Att.
__global__ __launch_bounds__(256) void attn_combine(
    const short* __restrict__ Opart, const float* __restrict__ Lpart,
    short* __restrict__ Att)
{
    int id = blockIdx.x * 256 + threadIdx.x;   // over H*NQ*HD = 2^20
    int d = id & 63;
    int q = (id >> 6) & (NQ - 1);
    int h = id >> 17;
    float L = 0.f, acc = 0.f;
#pragma unroll
    for (int s = 0; s < SPLIT; s++) {
        long b = (long)(s * H + h) * NQ + q;
        L   += Lpart[b];
        acc += bf2f(Opart[b * HD + d]);
    }
    Att[q * D + h * HD + d] = f2bf(acc / L);
}

// ---------------------------------------------------------------------------
// Fallback single-pass attention (exact online softmax) if ws is too small.
// Expects V row-major [NC][D], unscaled Q.
// ---------------------------------------------------------------------------
__global__ __launch_bounds__(256) void attn_mfma(
    const short* __restrict__ Q, const short* __restrict__ K,
    const short* __restrict__ V,
    const float* __restrict__ qc, const float* __restrict__ cc,
    const float* __restrict__ log_scale, const float* __restrict__ bph,
    short* __restrict__ out)
{
    __shared__ short Vt[HD][48];
    __shared__ short P[4][16][48];
    int wave = threadIdx.x >> 6, lane = threadIdx.x & 63;
    int h = blockIdx.y;
    int q0 = blockIdx.x * 64 + wave * 16;
    int quad = lane >> 4, l15 = lane & 15;
    const float scale = 0.125f;
    float bh = __expf(log_scale[0]) * bph[h];
    const short* qp = Q + (q0 + l15) * D + h * HD + quad * 8;
    short8 qa0 = *(const short8*)(qp);
    short8 qa1 = *(const short8*)(qp + 32);
    float qx[4], qy[4];
#pragma unroll
    for (int r = 0; r < 4; r++) {
        int q = q0 + quad * 4 + r;
        qx[r] = qc[q * 2]; qy[r] = qc[q * 2 + 1];
    }
    float m[4], l[4];
    float4v O[4];
#pragma unroll
    for (int r = 0; r < 4; r++) { m[r] = -1e30f; l[r] = 0.f; }
#pragma unroll
    for (int t = 0; t < 4; t++) O[t] = (float4v){0.f, 0.f, 0.f, 0.f};
    for (int c0 = 0; c0 < NC; c0 += 32) {
        __syncthreads();
        {
            int c = threadIdx.x >> 3;
            int dblk = (threadIdx.x & 7) * 8;
            short8 vv = *(const short8*)(V + (c0 + c) * D + h * HD + dblk);
#pragma unroll
            for (int j = 0; j < 8; j++) Vt[dblk + j][c] = vv[j];
        }
        const short* kp0 = K + (c0 + l15) * D + h * HD + quad * 8;
        const short* kp1 = kp0 + 16 * D;
        short8 kb00 = *(const short8*)(kp0);
        short8 kb01 = *(const short8*)(kp0 + 32);
        short8 kb10 = *(const short8*)(kp1);
        short8 kb11 = *(const short8*)(kp1 + 32);
        float4v s0 = {0,0,0,0}, s1 = {0,0,0,0};
        s0 = __builtin_amdgcn_mfma_f32_16x16x32_bf16(qa0, kb00, s0, 0, 0, 0);
        s0 = __builtin_amdgcn_mfma_f32_16x16x32_bf16(qa1, kb01, s0, 0, 0, 0);
        s1 = __builtin_amdgcn_mfma_f32_16x16x32_bf16(qa0, kb10, s1, 0, 0, 0);
        s1 = __builtin_amdgcn_mfma_f32_16x16x32_bf16(qa1, kb11, s1, 0, 0, 0);
        int cA = c0 + l15, cB = cA + 16;
        float cxA = cc[cA * 2], cyA = cc[cA * 2 + 1];
        float cxB = cc[cB * 2], cyB = cc[cB * 2 + 1];
#pragma unroll
        for (int r = 0; r < 4; r++) {
            float dxA = qx[r] - cxA, dyA = qy[r] - cyA;
            float dxB = qx[r] - cxB, dyB = qy[r] - cyB;
            float v0 = s0[r] * scale - bh * sqrtf(dxA * dxA + dyA * dyA);
            float v1 = s1[r] * scale - bh * sqrtf(dxB * dxB + dyB * dyB);
            float mx = fmaxf(v0, v1);
#pragma unroll
            for (int off = 1; off < 16; off <<= 1) mx = fmaxf(mx, __shfl_xor(mx, off));
            float mnew = fmaxf(m[r], mx);
            float alpha = __expf(m[r] - mnew);
            float p0 = __expf(v0 - mnew);
            float p1 = __expf(v1 - mnew);
            float ps = p0 + p1;
#pragma unroll
            for (int off = 1; off < 16; off <<= 1) ps += __shfl_xor(ps, off);
            l[r] = l[r] * alpha + ps;
            m[r] = mnew;
#pragma unroll
            for (int t = 0; t < 4; t++) O[t][r] *= alpha;
            P[wave][quad * 4 + r][l15]      = f2bf(p0);
            P[wave][quad * 4 + r][16 + l15] = f2bf(p1);
        }
        __syncthreads();
        short8 pa = *(const short8*)(&P[wave][l15][quad * 8]);
#pragma unroll
        for (int t = 0; t < 4; t++) {
            short8 vb = *(const short8*)(&Vt[t * 16 + l15][quad * 8]);
            O[t] = __builtin_amdgcn_mfma_f32_16x16x32_bf16(pa, vb, O[t], 0, 0, 0);
        }
    }
#pragma unroll
    for (int t = 0; t < 4; t++) {
#pragma unroll
        for (int r = 0; r < 4; r++) {
            int q = q0 + quad * 4 + r;
            out[q * D + h * HD + t * 16 + l15] = f2bf(O[t][r] / l[r]);
        }
    }
}

// ---------------------------------------------------------------------------
// Row LayerNorm: one wave per row of 512 f32, output f32.
// ---------------------------------------------------------------------------
__global__ __launch_bounds__(256) void layernorm_kernel(
    const float* __restrict__ X, const float* __restrict__ g,
    const float* __restrict__ b, float* __restrict__ out)
{
    int wave = threadIdx.x >> 6, lane = threadIdx.x & 63;
    int row = blockIdx.x * 4 + wave;
    const float* xp = X + row * D;
    float v[8];
    float s = 0.f;
#pragma unroll
    for (int i = 0; i < 8; i++) { v[i] = xp[lane + i * 64]; s += v[i]; }
#pragma unroll
    for (int off = 1; off < 64; off <<= 1) s += __shfl_xor(s, off);
    float mu = s * (1.f / D);
    float var = 0.f;
#pragma unroll
    for (int i = 0; i < 8; i++) { float d = v[i] - mu; var += d * d; }
#pragma unroll
    for (int off = 1; off < 64; off <<= 1) var += __shfl_xor(var, off);
    float rstd = rsqrtf(var * (1.f / D) + 1e-5f);
#pragma unroll
    for (int i = 0; i < 8; i++) {
        int c = lane + i * 64;
        out[row * D + c] = (v[i] - mu) * rstd * g[c] + b[c];
    }
}

extern "C" void kernel_launch(void* const* d_in, const int* in_sizes, int n_in,
                              void* d_out, int out_size, void* d_ws, size_t ws_size,
                              hipStream_t stream) {
    const float* query_repr     = (const float*)d_in[0];
    const float* context_repr   = (const float*)d_in[1];
    const float* query_coords   = (const float*)d_in[2];
    const float* context_coords = (const float*)d_in[3];
    const float* Wq = (const float*)d_in[4];
    const float* bq = (const float*)d_in[5];
    const float* Wk = (const float*)d_in[6];
    const float* bk = (const float*)d_in[7];
    const float* Wv = (const float*)d_in[8];
    const float* bv = (const float*)d_in[9];
    const float* Wo = (const float*)d_in[10];
    const float* bo = (const float*)d_in[11];
    const float* ln_g = (const float*)d_in[12];
    const float* ln_b = (const float*)d_in[13];
    const float* log_scale = (const float*)d_in[14];
    const float* bph = (const float*)d_in[15];

    short* ws = (short*)d_ws;
    short* Xq_bf = ws;                       // 1,048,576 shorts
    short* Xc_bf = Xq_bf + NQ * D;           // 2,097,152
    short* Wq_bf = Xc_bf + NC * D;           //   262,144 x4
    short* Wk_bf = Wq_bf + D * D;
    short* Wv_bf = Wk_bf + D * D;
    short* Wo_bf = Wv_bf + D * D;
    short* Qw  = Wo_bf + D * D;              // 1,048,576
    short* Kw  = Qw + NQ * D;                // 2,097,152
    short* Vw  = Kw + NC * D;                // 2,097,152 (Vp [D][NC] permuted)
    short* Att = Vw + NC * D;                // 1,048,576
    float* Xf  = (float*)(Att + NQ * D);     // 1,048,576 f32
    short* Opart = (short*)(Xf + NQ * D);    // SPLIT*H*NQ*HD bf16 = 16.8 MB
    float* Lpart = (float*)(Opart + (size_t)SPLIT * H * NQ * HD);  // 0.5 MB
    size_t ws_needed_split = ((char*)(Lpart + (size_t)SPLIT * H * NQ)) - (char*)d_ws;

    // 1. cast MFMA operands to bf16
    cast_all<<<dim3(4096), 256, 0, stream>>>(
        query_repr, context_repr, Wq, Wk, Wv, Wo, Xq_bf);

    // 2. Q projection (MFMA, 16x64 per wave)
    gemm_bt_bias<<<dim3((NQ / 16) * 8 / 4), 256, 0, stream>>>(Xq_bf, Wq_bf, bq, Qw, NQ);

    // 3. K+V projections + attention
    if (ws_size >= ws_needed_split) {
        // merged K/V projection (shared A-frags); V transposed+permuted.
        gemm_bt_bias_kv<<<dim3((NC / 16) * 8 / 4), 256, 0, stream>>>(
            Xc_bf, Wk_bf, Wv_bf, bk, bv, Kw, Vw, NC);
        attn_mfma_split9<<<dim3(NQ / 64, H / 2, SPLIT), 256, 0, stream>>>(
            Qw, Kw, Vw, query_coords, context_coords, log_scale, bph,
            Opart, Lpart);
        attn_combine<<<dim3(H * NQ * HD / 256), 256, 0, stream>>>(
            Opart, Lpart, Att);
    } else {
        gemm_bt_bias<<<dim3((NC / 16) * 8 / 4), 256, 0, stream>>>(
            Xc_bf, Wk_bf, bk, Kw, NC);
        gemm_bt_bias<<<dim3((NC / 16) * 8 / 4), 256, 0, stream>>>(
            Xc_bf, Wv_bf, bv, Vw, NC);
        attn_mfma<<<dim3(NQ / 64, H), 256, 0, stream>>>(
            Qw, Kw, Vw, query_coords, context_coords, log_scale, bph, Att);
    }

    // 4. output projection + residual (MFMA, f32 out)
    gemm_bt_bias_res_f32<<<dim3((NQ / 16) * 8 / 4), 256, 0, stream>>>(
        Att, Wo_bf, bo, query_repr, Xf, NQ);

    // 5. LayerNorm -> f32 output
    layernorm_kernel<<<dim3(NQ / 4), 256, 0, stream>>>(Xf, ln_g, ln_b, (float*)d_out);
}